// Round 8
// baseline (162.278 us; speedup 1.0000x reference)
//
#include <hip/hip_runtime.h>
#include <math.h>

// ---------------------------------------------------------------------------
// Shapes:
// t_feat3/s_feat3: [4][64][48][48]  (147456 per batch) -> viewed flat [2304][64]
// t_feat4/s_feat4: [4][128][24][24]
// t_out/s_out:     [4][21][128][128] (344064 per batch, 16384 per class)
// W_B/W_C: [64][64][3][3], b_B/b_C: [64]
// Output: s_out copy (1376256 floats) then pa, pi, ic, lo, SA scalars.
// ---------------------------------------------------------------------------

typedef __attribute__((ext_vector_type(8))) short short8;   // 8 bf16 (4 VGPR)
typedef __attribute__((ext_vector_type(4))) float f32x4;
typedef __attribute__((ext_vector_type(8))) unsigned short u16x8;
typedef __attribute__((ext_vector_type(4))) unsigned short u16x4;

#define INV_SQRT48 0.14433756729740643f

static __device__ __forceinline__ unsigned short f2bf(float x) {
  unsigned int u = __float_as_uint(x);
  unsigned int r = (u + 0x7fffu + ((u >> 16) & 1u)) >> 16;
  return (unsigned short)r;
}

// ========== t3 -> bf16 convert, pre-scaled by 1/sqrt(48) (SA-only use) ======
__global__ __launch_bounds__(256) void cvt_kernel(const float* __restrict__ in,
                                                  unsigned short* __restrict__ out) {
  int i = (blockIdx.x * 256 + threadIdx.x) * 8;
  float4 a = *(const float4*)(in + i);
  float4 b = *(const float4*)(in + i + 4);
  u16x8 v;
  v[0] = f2bf(a.x * INV_SQRT48); v[1] = f2bf(a.y * INV_SQRT48);
  v[2] = f2bf(a.z * INV_SQRT48); v[3] = f2bf(a.w * INV_SQRT48);
  v[4] = f2bf(b.x * INV_SQRT48); v[5] = f2bf(b.y * INV_SQRT48);
  v[6] = f2bf(b.z * INV_SQRT48); v[7] = f2bf(b.w * INV_SQRT48);
  *(u16x8*)(out + i) = v;
}

// =============== s3 -> transposed bf16 [b][pix(2304)][ic(64)] ===============
__global__ __launch_bounds__(256) void transpose_kernel(
    const float* __restrict__ s3, unsigned short* __restrict__ Ts) {
  __shared__ float ld[64][65];
  int b = blockIdx.y;
  int p0 = blockIdx.x * 64;
  int tid = threadIdx.x;
  const float* src = s3 + b * 147456;
#pragma unroll
  for (int q = tid; q < 1024; q += 256) {
    int ic = q >> 4; int px = (q & 15) * 4;
    float4 v = *(const float4*)(src + ic * 2304 + p0 + px);
    ld[ic][px] = v.x; ld[ic][px + 1] = v.y; ld[ic][px + 2] = v.z; ld[ic][px + 3] = v.w;
  }
  __syncthreads();
  int pix = tid >> 2, icg = (tid & 3) * 16;
  u16x8 o0, o1;
#pragma unroll
  for (int j = 0; j < 8; j++) o0[j] = f2bf(ld[icg + j][pix]);
#pragma unroll
  for (int j = 0; j < 8; j++) o1[j] = f2bf(ld[icg + 8 + j][pix]);
  unsigned short* dst = Ts + b * 147456 + (p0 + pix) * 64 + icg;
  *(u16x8*)dst = o0;
  *(u16x8*)(dst + 8) = o1;
}

// ======= weight pack: [oc][ic][3][3] f32 -> [conv][tap][oc][ic] bf16 ========
__global__ __launch_bounds__(256) void pack_w_kernel(
    const float* __restrict__ WB, const float* __restrict__ WC,
    unsigned short* __restrict__ Wp) {
  int idx = blockIdx.x * 256 + threadIdx.x;   // 0..73727
  int conv = idx / 36864;
  int r = idx - conv * 36864;
  int tap = r >> 12;
  int r2 = r & 4095;
  int oc = r2 >> 6, ic = r2 & 63;
  const float* W = conv ? WC : WB;
  Wp[idx] = f2bf(W[oc * 576 + ic * 9 + tap]);
}

// ================== conv3x3 as 9-tap implicit GEMM (MFMA) ===================
// Output pre-scaled by 1/sqrt(48) (consumed only by SA).
__global__ __launch_bounds__(256) void conv_mfma_kernel(
    const unsigned short* __restrict__ Ts, const unsigned short* __restrict__ Wp,
    const float* __restrict__ bB, const float* __restrict__ bC,
    unsigned short* __restrict__ Ab, unsigned short* __restrict__ Ac) {
  int b = blockIdx.y;
  int ptile = blockIdx.x;            // 0..143, 16 pixels each
  int tid = threadIdx.x;
  int wave = tid >> 6, lane = tid & 63;
  int conv = wave & 1;               // 0=B, 1=C
  int ochalf = wave >> 1;            // oc base = ochalf*32
  int lrow = lane & 15, kblk = lane >> 4;
  int p = ptile * 16 + lrow;         // this lane's A row (pixel)
  int y = p / 48, x = p - y * 48;
  const unsigned short* Tb = Ts + b * 147456;
  const unsigned short* Wc = Wp + conv * 36864;
  const short8 zz = {0, 0, 0, 0, 0, 0, 0, 0};
  f32x4 acc0 = {0.f, 0.f, 0.f, 0.f}, acc1 = {0.f, 0.f, 0.f, 0.f};
#pragma unroll
  for (int t = 0; t < 9; t++) {
    const int dy = t / 3 - 1, dx = t % 3 - 1;
    int yy = y + dy, xx = x + dx;
    bool valid = ((unsigned)yy < 48u) && ((unsigned)xx < 48u);
    int spix = valid ? (p + dy * 48 + dx) : p;
    const unsigned short* ap = Tb + spix * 64 + kblk * 8;
    short8 a0 = *(const short8*)ap;
    short8 a1 = *(const short8*)(ap + 32);
    if (!valid) { a0 = zz; a1 = zz; }
    const unsigned short* wp0 = Wc + (t * 64 + ochalf * 32 + lrow) * 64 + kblk * 8;
    short8 b00 = *(const short8*)wp0;
    short8 b01 = *(const short8*)(wp0 + 32);
    short8 b10 = *(const short8*)(wp0 + 1024);        // +16 oc rows
    short8 b11 = *(const short8*)(wp0 + 1024 + 32);
    acc0 = __builtin_amdgcn_mfma_f32_16x16x32_bf16(a0, b00, acc0, 0, 0, 0);
    acc0 = __builtin_amdgcn_mfma_f32_16x16x32_bf16(a1, b01, acc0, 0, 0, 0);
    acc1 = __builtin_amdgcn_mfma_f32_16x16x32_bf16(a0, b10, acc1, 0, 0, 0);
    acc1 = __builtin_amdgcn_mfma_f32_16x16x32_bf16(a1, b11, acc1, 0, 0, 0);
  }
  const float* bias = conv ? bC : bB;
  unsigned short* dst = conv ? Ac : Ab;
  int oc0 = ochalf * 32 + lrow;
  int oc1 = oc0 + 16;
  float bi0 = bias[oc0], bi1 = bias[oc1];
  int pixb = ptile * 16 + kblk * 4;
  u16x4 o0, o1;
#pragma unroll
  for (int i = 0; i < 4; i++) {
    o0[i] = f2bf((acc0[i] + bi0) * INV_SQRT48);
    o1[i] = f2bf((acc1[i] + bi1) * INV_SQRT48);
  }
  *(u16x4*)(dst + b * 147456 + oc0 * 2304 + pixb) = o0;
  *(u16x4*)(dst + b * 147456 + oc1 * 2304 + pixb) = o1;
}

// ========= SA phase 1: LDS-staged (global_load_lds) MFMA + row stats ========
// Block: 64 rows x 128-col chunk (blockIdx.z of 18). 4 stages of 32 cols,
// double-buffered global_load_lds with pre-swizzled source + XOR'd ds_read.
// Grid 36x4x18 = 2592 blocks -> ~10 blocks/CU; LDS 16KB -> 8 resident
// blocks/CU (32 waves/CU) so per-stage latency overlaps across blocks.
__global__ __launch_bounds__(256) void sa_partial_kernel(
    const unsigned short* __restrict__ T16, const unsigned short* __restrict__ Ab16,
    const unsigned short* __restrict__ Ac16, float* __restrict__ rowstats) {
  __shared__ __align__(16) unsigned short lbuf[2][2][2048];  // [buf][T/Ac][32x64] 16KB
  int b = blockIdx.y, zc = blockIdx.z;
  int r0 = blockIdx.x * 64;
  const unsigned short* Tb = T16 + b * 147456;
  const unsigned short* Abb = Ab16 + b * 147456;
  const unsigned short* Acb = Ac16 + b * 147456;
  int tid = threadIdx.x, wave = tid >> 6, lane = tid & 63;
  int lrow = lane & 15, kblk = lane >> 4;
  int grow_base = r0 + wave * 16;
  // loop-invariant row-side fragments (registers)
  const short8 at0 = *(const short8*)(Tb + (grow_base + lrow) * 64 + kblk * 8);
  const short8 at1 = *(const short8*)(Tb + (grow_base + lrow) * 64 + 32 + kblk * 8);
  const short8 ar0 = *(const short8*)(Abb + (grow_base + lrow) * 64 + kblk * 8);
  const short8 ar1 = *(const short8*)(Abb + (grow_base + lrow) * 64 + 32 + kblk * 8);
  // staging role: waves 0,1 stage T halves; waves 2,3 stage Ac halves
  const unsigned short* sarr = (wave & 2) ? Acb : Tb;
  int aw = wave >> 1, hw = wave & 1;

  float Sx[4] = {0.f, 0.f, 0.f, 0.f}, Sa[4] = {0.f, 0.f, 0.f, 0.f};
  float Sa2[4] = {0.f, 0.f, 0.f, 0.f}, Zb[4] = {0.f, 0.f, 0.f, 0.f};
  float Qq[4] = {0.f, 0.f, 0.f, 0.f}, Ww[4] = {0.f, 0.f, 0.f, 0.f};

#define SA_STAGE(s_, p_)                                                        \
  {                                                                             \
    int n0_ = zc * 128 + (s_) * 32;                                             \
    const char* gb_ = (const char*)(sarr + n0_ * 64);                           \
    char* lb_ = (char*)(&lbuf[(p_)][aw][0]);                                    \
    _Pragma("unroll")                                                           \
    for (int j_ = 0; j_ < 2; j_++) {                                            \
      int d_ = hw * 2048 + j_ * 1024 + lane * 16;                               \
      int g_ = d_ ^ (((d_ >> 7) & 7) << 4);                                     \
      __builtin_amdgcn_global_load_lds(                                         \
          (const __attribute__((address_space(1))) unsigned int*)(gb_ + g_),    \
          (__attribute__((address_space(3))) unsigned int*)(lb_ + hw * 2048 + j_ * 1024), \
          16, 0, 0);                                                            \
    }                                                                           \
  }

  SA_STAGE(0, 0);
  __syncthreads();               // compiler drains vmcnt before barrier
  for (int s = 0; s < 4; s++) {
    int p = s & 1;
    if (s < 3) SA_STAGE(s + 1, p ^ 1);   // async prefetch into other buffer
    int n0 = zc * 128 + s * 32;
    const char* lbT = (const char*)&lbuf[p][0][0];
    const char* lbC = (const char*)&lbuf[p][1][0];
    int sw = (lrow & 7) << 4;
#pragma unroll
    for (int ctl = 0; ctl < 2; ctl++) {
      int abase = (ctl * 16 + lrow) * 128 + kblk * 16;
      short8 bt0 = *(const short8*)(lbT + (abase ^ sw));
      short8 bt1 = *(const short8*)(lbT + ((abase + 64) ^ sw));
      short8 bc0 = *(const short8*)(lbC + (abase ^ sw));
      short8 bc1 = *(const short8*)(lbC + ((abase + 64) ^ sw));
      f32x4 accA = {0.f, 0.f, 0.f, 0.f}, accV = {0.f, 0.f, 0.f, 0.f};
      accA = __builtin_amdgcn_mfma_f32_16x16x32_bf16(at0, bt0, accA, 0, 0, 0);
      accA = __builtin_amdgcn_mfma_f32_16x16x32_bf16(at1, bt1, accA, 0, 0, 0);
      accV = __builtin_amdgcn_mfma_f32_16x16x32_bf16(ar0, bc0, accV, 0, 0, 0);
      accV = __builtin_amdgcn_mfma_f32_16x16x32_bf16(ar1, bc1, accV, 0, 0, 0);
      int col = n0 + ctl * 16 + lrow;
#pragma unroll
      for (int i = 0; i < 4; i++) {
        int row = grow_base + kblk * 4 + i;
        float a = accA[i];
        float v = accV[i];
        if (row == col) { a = 0.f; v = 0.f; }
        float ea = __expf(a), eb = __expf(v);
        Sx[i] += ea; Sa[i] += a; Sa2[i] += a * a;
        Zb[i] += eb; Qq[i] += eb * eb; Ww[i] += a * eb;
      }
    }
    __syncthreads();             // next buffer staged; current free for reuse
  }
  // butterfly over the 16 column-lanes of each kblk group
#pragma unroll
  for (int m = 1; m < 16; m <<= 1) {
#pragma unroll
    for (int i = 0; i < 4; i++) {
      Sx[i] += __shfl_xor(Sx[i], m);
      Sa[i] += __shfl_xor(Sa[i], m);
      Sa2[i] += __shfl_xor(Sa2[i], m);
      Zb[i] += __shfl_xor(Zb[i], m);
      Qq[i] += __shfl_xor(Qq[i], m);
      Ww[i] += __shfl_xor(Ww[i], m);
    }
  }
  if (lrow == 0) {
#pragma unroll
    for (int i = 0; i < 4; i++) {
      float* rp = &rowstats[(b * 2304 + grow_base + kblk * 4 + i) * 6];
      atomicAdd(rp + 0, Sx[i]);
      atomicAdd(rp + 1, Sa[i]);
      atomicAdd(rp + 2, Sa2[i]);
      atomicAdd(rp + 3, Zb[i]);
      atomicAdd(rp + 4, Qq[i]);
      atomicAdd(rp + 5, Ww[i]);
    }
  }
#undef SA_STAGE
}

// ========= SA phase 2: rowloss from full stats, reduce to acc[1] ============
__global__ __launch_bounds__(256) void sa_final_kernel(
    const float* __restrict__ rowstats, float* __restrict__ acc) {
  int row = blockIdx.x * 256 + threadIdx.x;   // 0..9215
  const float* st = rowstats + row * 6;
  float vSx = st[0], vSa = st[1], vSa2 = st[2];
  float vZb = st[3], vQq = st[4], vWw = st[5];
  float L = __logf(vSx);
  float rl = vSa2 - 2.f * L * vSa + 2304.f * L * L + 2.f * L
             - 2.f * (vWw / vZb) + vQq / (vZb * vZb);
  __shared__ float red[4];
#pragma unroll
  for (int m = 1; m < 64; m <<= 1) rl += __shfl_xor(rl, m);
  if ((threadIdx.x & 63) == 0) red[threadIdx.x >> 6] = rl;
  __syncthreads();
  if (threadIdx.x == 0)
    atomicAdd(&acc[1], red[0] + red[1] + red[2] + red[3]);
}

// ============================ pa: maxpool 12x12 =============================
__global__ __launch_bounds__(256) void pool_kernel(
    const float* __restrict__ t4, const float* __restrict__ s4,
    float* __restrict__ pooled_t, float* __restrict__ pooled_s) {
  int widx = blockIdx.x * 4 + (threadIdx.x >> 6);  // 0..2047
  int lane = threadIdx.x & 63;
  int p = widx & 3, bc = widx >> 2;
  int py = p >> 1, px = p & 1;
  int base = bc * 576 + py * 288 + px * 12;
  float mt = -1e30f, ms = -1e30f;
  for (int e = lane; e < 144; e += 64) {
    int iy = e / 12, ix = e - iy * 12;
    int off = base + iy * 24 + ix;
    mt = fmaxf(mt, t4[off]);
    ms = fmaxf(ms, s4[off]);
  }
#pragma unroll
  for (int d = 1; d < 64; d <<= 1) {
    mt = fmaxf(mt, __shfl_xor(mt, d));
    ms = fmaxf(ms, __shfl_xor(ms, d));
  }
  if (lane == 0) { pooled_t[widx] = mt; pooled_s[widx] = ms; }
}

__global__ __launch_bounds__(256) void pa_final_kernel(
    const float* __restrict__ pooled_t, const float* __restrict__ pooled_s,
    float* __restrict__ acc) {
  __shared__ float ps[2048], pt[2048], nrm[32], sim[128];
  int tid = threadIdx.x;
  for (int q = tid; q < 2048; q += 256) { ps[q] = pooled_s[q]; pt[q] = pooled_t[q]; }
  __syncthreads();
  if (tid < 32) {
    int tens = tid >> 4, r = tid & 15, b = r >> 2, p = r & 3;
    const float* v = tens ? pt : ps;
    float s = 0.f;
    for (int c = 0; c < 128; c++) { float x = v[(b * 128 + c) * 4 + p]; s += x * x; }
    nrm[tid] = sqrtf(s) + 1e-8f;
  }
  __syncthreads();
  if (tid < 128) {
    int tens = tid >> 6, r = tid & 63, b = r >> 4, m = (r >> 2) & 3, n = r & 3;
    const float* v = tens ? pt : ps;
    float s = 0.f;
    for (int c = 0; c < 128; c++)
      s += v[(b * 128 + c) * 4 + m] * v[(b * 128 + c) * 4 + n];
    sim[tid] = s / (nrm[tens * 16 + b * 4 + m] * nrm[tens * 16 + b * 4 + n]);
  }
  __syncthreads();
  if (tid < 64) {
    float df = sim[64 + tid] - sim[tid];
    float d = df * df;
#pragma unroll
    for (int k = 1; k < 64; k <<= 1) d += __shfl_xor(d, k);
    if (tid == 0) acc[4] = d;   // raw; finalize /64
  }
}

// ================================ pi (KL) ===================================
__global__ __launch_bounds__(256) void pi_kernel(
    const float* __restrict__ t_out, const float* __restrict__ s_out,
    float* __restrict__ acc) {
  int idx = blockIdx.x * 256 + threadIdx.x;  // 0..65535
  int b = idx >> 14, rem = idx & 16383;
  const float* tp = t_out + b * 344064 + rem;
  const float* sp = s_out + b * 344064 + rem;
  float t[21], s[21];
#pragma unroll
  for (int c = 0; c < 21; c++) { t[c] = tp[c * 16384]; s[c] = sp[c * 16384]; }
  float mt = t[0], ms = s[0];
#pragma unroll
  for (int c = 1; c < 21; c++) { mt = fmaxf(mt, t[c]); ms = fmaxf(ms, s[c]); }
  float Zt = 0.f, Zs = 0.f;
#pragma unroll
  for (int c = 0; c < 21; c++) { Zt += __expf(t[c] - mt); Zs += __expf(s[c] - ms); }
  float lt = __logf(Zt), ls = __logf(Zs);
  float sum = 0.f;
#pragma unroll
  for (int c = 0; c < 21; c++) {
    float lq = t[c] - mt - lt;
    float lp = s[c] - ms - ls;
    sum += __expf(lq) * (lq - lp);
  }
  __shared__ float red[4];
#pragma unroll
  for (int k = 1; k < 64; k <<= 1) sum += __shfl_xor(sum, k);
  if ((threadIdx.x & 63) == 0) red[threadIdx.x >> 6] = sum;
  __syncthreads();
  if (threadIdx.x == 0) atomicAdd(&acc[0], red[0] + red[1] + red[2] + red[3]);
}

// ========== unified MFMA 21x21 grams: ic (raw) + lo cross (P=softmax) =======
#define GR_PAD 136
__global__ __launch_bounds__(256) void gram_mfma_kernel(
    const float* __restrict__ s_out, const float* __restrict__ t_out,
    const float* __restrict__ zrbuf, float* __restrict__ Gs,
    float* __restrict__ Gt, float* __restrict__ cross) {
  __shared__ unsigned short st[4][32][GR_PAD];   // 34816 B; aliased as red later
  int job = blockIdx.y;
  int kind = job >> 3, tens = (job >> 2) & 1, b = job & 3;
  const float* x = (tens ? t_out : s_out) + b * 344064;
  const float* zr = zrbuf + ((tens * 4 + b) * 21) * 128;
  int tid = threadIdx.x, wave = tid >> 6, lane = tid & 63;
  int lrow = lane & 15, kblk = lane >> 4;
#pragma unroll
  for (int r = 21; r < 32; r++)
    *(unsigned int*)&st[wave][r][lane * 2] = 0u;
  f32x4 a00 = {0.f, 0.f, 0.f, 0.f}, a01 = {0.f, 0.f, 0.f, 0.f};
  f32x4 a11 = {0.f, 0.f, 0.f, 0.f};
#pragma unroll
  for (int slab = 0; slab < 2; slab++) {
    int k0 = blockIdx.x * 1024 + wave * 256 + slab * 128;
    for (int c = 0; c < 21; c++) {
      float2 v = *(const float2*)(x + c * 16384 + k0 + lane * 2);
      if (kind) {
        float2 z2 = *(const float2*)(zr + c * 128 + ((lane * 2) & 127));
        v.x = __expf(v.x) * z2.x;
        v.y = __expf(v.y) * z2.y;
      }
      unsigned int pk = (unsigned int)f2bf(v.x) | ((unsigned int)f2bf(v.y) << 16);
      *(unsigned int*)&st[wave][c][lane * 2] = pk;
    }
#pragma unroll
    for (int kk = 0; kk < 4; kk++) {
      short8 A0 = *(const short8*)&st[wave][lrow][kk * 32 + kblk * 8];
      short8 A1 = *(const short8*)&st[wave][16 + lrow][kk * 32 + kblk * 8];
      a00 = __builtin_amdgcn_mfma_f32_16x16x32_bf16(A0, A0, a00, 0, 0, 0);
      a01 = __builtin_amdgcn_mfma_f32_16x16x32_bf16(A0, A1, a01, 0, 0, 0);
      a11 = __builtin_amdgcn_mfma_f32_16x16x32_bf16(A1, A1, a11, 0, 0, 0);
    }
  }
  __syncthreads();
  float* red = (float*)&st[0][0][0];   // [4][3][16][16]
#pragma unroll
  for (int i = 0; i < 4; i++) {
    int m = kblk * 4 + i;
    red[((wave * 3 + 0) * 16 + m) * 16 + lrow] = a00[i];
    red[((wave * 3 + 1) * 16 + m) * 16 + lrow] = a01[i];
    red[((wave * 3 + 2) * 16 + m) * 16 + lrow] = a11[i];
  }
  __syncthreads();
  if (tid < 441) {
    int i = tid / 21, j = tid - i * 21;
    float s = 0.f;
#pragma unroll
    for (int w = 0; w < 4; w++) {
      float v;
      if (i < 16)
        v = (j < 16) ? red[((w * 3 + 0) * 16 + i) * 16 + j]
                     : red[((w * 3 + 1) * 16 + i) * 16 + (j - 16)];
      else
        v = (j < 16) ? red[((w * 3 + 1) * 16 + j) * 16 + (i - 16)]
                     : red[((w * 3 + 2) * 16 + (i - 16)) * 16 + (j - 16)];
      s += v;
    }
    float* dst = kind ? (cross + tens * 441) : ((tens ? Gt : Gs) + b * 441);
    atomicAdd(&dst[i * 21 + j], s);
  }
}

__global__ __launch_bounds__(512) void ic_final_kernel(
    const float* __restrict__ Gs, const float* __restrict__ Gt,
    float* __restrict__ acc) {
  __shared__ float gs[441], gt[441], ns[21], nt_[21], rd[8];
  int tid = threadIdx.x;
  float total = 0.f;
  for (int b = 0; b < 4; b++) {
    __syncthreads();
    if (tid < 441) { gs[tid] = Gs[b * 441 + tid]; gt[tid] = Gt[b * 441 + tid]; }
    __syncthreads();
    if (tid < 21) {
      float a = 0.f, c2 = 0.f;
      for (int j = 0; j < 21; j++) {
        a += gs[tid * 21 + j] * gs[tid * 21 + j];
        c2 += gt[tid * 21 + j] * gt[tid * 21 + j];
      }
      ns[tid] = fmaxf(sqrtf(a), 1e-12f);
      nt_[tid] = fmaxf(sqrtf(c2), 1e-12f);
    }
    __syncthreads();
    if (tid < 441) {
      int i = tid / 21;
      float d = gs[tid] / ns[i] - gt[tid] / nt_[i];
      total += d * d;
    }
  }
#pragma unroll
  for (int k = 1; k < 64; k <<= 1) total += __shfl_xor(total, k);
  if ((tid & 63) == 0) rd[tid >> 6] = total;
  __syncthreads();
  if (tid == 0) {
    float s = 0.f;
    for (int i = 0; i < 8; i++) s += rd[i];
    acc[2] = s;
  }
}

// ============================ lo (pairwise KL) ==============================
__global__ __launch_bounds__(128) void lo_stats_kernel(
    const float* __restrict__ s_out, const float* __restrict__ t_out,
    float* __restrict__ zrbuf, float* __restrict__ self_ent) {
  int c = blockIdx.x, b = blockIdx.y, tens = blockIdx.z;
  const float* x = (tens ? t_out : s_out) + b * 344064 + c * 16384;
  int w = threadIdx.x;
  float Z = 0.f, U = 0.f;
#pragma unroll 4
  for (int h = 0; h < 128; h++) {
    float v = x[h * 128 + w];
    float e = __expf(v);
    Z += e; U += v * e;
  }
  int idx = ((tens * 4 + b) * 21 + c) * 128 + w;
  zrbuf[idx] = 1.0f / Z;
  float se = U / Z - __logf(Z);
#pragma unroll
  for (int k = 1; k < 64; k <<= 1) se += __shfl_xor(se, k);
  __shared__ float r2[2];
  if ((w & 63) == 0) r2[w >> 6] = se;
  __syncthreads();
  if (w == 0) atomicAdd(&self_ent[tens * 21 + c], r2[0] + r2[1]);
}

__global__ __launch_bounds__(512) void lo_final_kernel(
    const float* __restrict__ self_ent, const float* __restrict__ cross,
    float* __restrict__ acc) {
  __shared__ float Ks[441], Kt[441], ns[21], nt_[21], rd[8];
  int tid = threadIdx.x;
  if (tid < 441) {
    int i = tid / 21, j = tid - i * 21;
    int mx_ = i > j ? i : j;
    Ks[tid] = (self_ent[mx_] - cross[tid]) * 0.25f;
    Kt[tid] = (self_ent[21 + mx_] - cross[441 + tid]) * 0.25f;
  }
  __syncthreads();
  if (tid < 21) {
    float a = 0.f, b2 = 0.f;
    for (int j = 0; j < 21; j++) {
      a += Ks[tid * 21 + j] * Ks[tid * 21 + j];
      b2 += Kt[tid * 21 + j] * Kt[tid * 21 + j];
    }
    ns[tid] = fmaxf(sqrtf(a), 1e-12f);
    nt_[tid] = fmaxf(sqrtf(b2), 1e-12f);
  }
  __syncthreads();
  float tot = 0.f;
  if (tid < 441) {
    int i = tid / 21;
    float d = Ks[tid] / ns[i] - Kt[tid] / nt_[i];
    tot = d * d;
  }
#pragma unroll
  for (int k = 1; k < 64; k <<= 1) tot += __shfl_xor(tot, k);
  if ((tid & 63) == 0) rd[tid >> 6] = tot;
  __syncthreads();
  if (tid == 0) {
    float s = 0.f;
    for (int i = 0; i < 8; i++) s += rd[i];
    acc[3] = s;
  }
}

// ================================ finalize ==================================
__global__ void finalize_kernel(const float* __restrict__ acc, float* __restrict__ out) {
  out[0] = acc[4] * (1.0f / 64.0f);                 // pa_loss
  out[1] = acc[0] * (1.0f / 1376256.0f);            // pi_loss
  out[2] = acc[2] * (1.0f / 84.0f);                 // ic_loss
  out[3] = acc[3] * (1.0f / 1764.0f);               // lo_loss
  out[4] = sqrtf(acc[1]) * (1.0f / 21233664.0f);    // SA_loss (4*2304^2)
}

// ============================================================================
extern "C" void kernel_launch(void* const* d_in, const int* in_sizes, int n_in,
                              void* d_out, int out_size, void* d_ws, size_t ws_size,
                              hipStream_t stream) {
  const float* t3 = (const float*)d_in[0];
  const float* s3 = (const float*)d_in[1];
  const float* t4 = (const float*)d_in[2];
  const float* s4 = (const float*)d_in[3];
  const float* t_out = (const float*)d_in[4];
  const float* s_out = (const float*)d_in[5];
  const float* WB = (const float*)d_in[6];
  const float* bB = (const float*)d_in[7];
  const float* WC = (const float*)d_in[8];
  const float* bC = (const float*)d_in[9];
  float* out = (float*)d_out;
  float* ws = (float*)d_ws;

  float* acc = ws;                           // 8
  float* self_ent = ws + 8;                  // 42
  float* cross = ws + 50;                    // 882
  float* Gs = ws + 932;                      // 1764
  float* Gt = ws + 2696;                     // 1764 -> 4460
  float* pooled_s = ws + 4460;               // 2048
  float* pooled_t = ws + 6508;               // 2048
  float* zrbuf = ws + 8556;                  // 21504 -> 30060
  unsigned short* T16u = (unsigned short*)(ws + 30060);    // 589824 bf16
  unsigned short* Ab16u = (unsigned short*)(ws + 324972);  // 589824 bf16
  unsigned short* Ac16u = (unsigned short*)(ws + 619884);  // 589824 bf16
  unsigned short* Ts16u = (unsigned short*)(ws + 914796);  // 589824 bf16
  unsigned short* Wp16u = (unsigned short*)(ws + 1209708); // 73728 bf16
  // rowstats aliases Ts16u (dead after conv_mfma): 9216 rows x 6 f32 = 55296 f
  float* rowstats = (float*)Ts16u;

  hipMemsetAsync(ws, 0, 4460 * sizeof(float), stream);
  hipMemcpyAsync(d_out, (const void*)s_out, 1376256 * sizeof(float),
                 hipMemcpyDeviceToDevice, stream);

  cvt_kernel<<<288, 256, 0, stream>>>(t3, T16u);
  transpose_kernel<<<dim3(36, 4), 256, 0, stream>>>(s3, Ts16u);
  pack_w_kernel<<<288, 256, 0, stream>>>(WB, WC, Wp16u);
  conv_mfma_kernel<<<dim3(144, 4), 256, 0, stream>>>(Ts16u, Wp16u, bB, bC, Ab16u, Ac16u);
  // Ts16u dead from here; reuse as rowstats (zero it first, on-stream)
  hipMemsetAsync(rowstats, 0, 55296 * sizeof(float), stream);
  sa_partial_kernel<<<dim3(36, 4, 18), 256, 0, stream>>>(T16u, Ab16u, Ac16u, rowstats);
  sa_final_kernel<<<36, 256, 0, stream>>>(rowstats, acc);
  pool_kernel<<<512, 256, 0, stream>>>(t4, s4, pooled_t, pooled_s);
  pa_final_kernel<<<1, 256, 0, stream>>>(pooled_t, pooled_s, acc);
  pi_kernel<<<256, 256, 0, stream>>>(t_out, s_out, acc);
  lo_stats_kernel<<<dim3(21, 4, 2), 128, 0, stream>>>(s_out, t_out, zrbuf, self_ent);
  gram_mfma_kernel<<<dim3(16, 16), 256, 0, stream>>>(s_out, t_out, zrbuf, Gs, Gt, cross);
  ic_final_kernel<<<1, 512, 0, stream>>>(Gs, Gt, acc);
  lo_final_kernel<<<1, 512, 0, stream>>>(self_ent, cross, acc);
  finalize_kernel<<<1, 1, 0, stream>>>(acc, out + 1376256);
}

// Round 9
// 114.556 us; speedup vs baseline: 1.4166x; 1.4166x over previous
//
#include <hip/hip_runtime.h>
#include <math.h>

// ---------------------------------------------------------------------------
// Shapes:
// t_feat3/s_feat3: [4][64][48][48]  (147456 per batch) -> viewed flat [2304][64]
// t_feat4/s_feat4: [4][128][24][24]
// t_out/s_out:     [4][21][128][128] (344064 per batch, 16384 per class)
// W_B/W_C: [64][64][3][3], b_B/b_C: [64]
// Output: s_out copy (1376256 floats) then pa, pi, ic, lo, SA scalars.
// ---------------------------------------------------------------------------

typedef __attribute__((ext_vector_type(8))) short short8;   // 8 bf16 (4 VGPR)
typedef __attribute__((ext_vector_type(4))) float f32x4;
typedef __attribute__((ext_vector_type(8))) unsigned short u16x8;
typedef __attribute__((ext_vector_type(4))) unsigned short u16x4;

#define INV_SQRT48 0.14433756729740643f

static __device__ __forceinline__ unsigned short f2bf(float x) {
  unsigned int u = __float_as_uint(x);
  unsigned int r = (u + 0x7fffu + ((u >> 16) & 1u)) >> 16;
  return (unsigned short)r;
}

// ===== fused preprocessing: cvt (288 blk) | transpose (144) | pack_w (288) ==
__global__ __launch_bounds__(256) void prep_kernel(
    const float* __restrict__ t3, const float* __restrict__ s3,
    const float* __restrict__ WB, const float* __restrict__ WC,
    unsigned short* __restrict__ T16, unsigned short* __restrict__ Ts,
    unsigned short* __restrict__ Wp) {
  __shared__ float ld[64][65];
  int bx = blockIdx.x;
  int tid = threadIdx.x;
  if (bx < 288) {
    // t3 -> bf16 pre-scaled by 1/sqrt(48)
    int i = (bx * 256 + tid) * 8;
    float4 a = *(const float4*)(t3 + i);
    float4 b = *(const float4*)(t3 + i + 4);
    u16x8 v;
    v[0] = f2bf(a.x * INV_SQRT48); v[1] = f2bf(a.y * INV_SQRT48);
    v[2] = f2bf(a.z * INV_SQRT48); v[3] = f2bf(a.w * INV_SQRT48);
    v[4] = f2bf(b.x * INV_SQRT48); v[5] = f2bf(b.y * INV_SQRT48);
    v[6] = f2bf(b.z * INV_SQRT48); v[7] = f2bf(b.w * INV_SQRT48);
    *(u16x8*)(T16 + i) = v;
  } else if (bx < 432) {
    // s3 -> transposed bf16 [b][pix][ic]
    int t = bx - 288;
    int b = t / 36;
    int p0 = (t - b * 36) * 64;
    const float* src = s3 + b * 147456;
#pragma unroll
    for (int q = tid; q < 1024; q += 256) {
      int ic = q >> 4; int px = (q & 15) << 2;
      float4 v = *(const float4*)(src + ic * 2304 + p0 + px);
      ld[ic][px] = v.x; ld[ic][px + 1] = v.y; ld[ic][px + 2] = v.z; ld[ic][px + 3] = v.w;
    }
    __syncthreads();
    int pix = tid >> 2, icg = (tid & 3) * 16;
    u16x8 o0, o1;
#pragma unroll
    for (int j = 0; j < 8; j++) o0[j] = f2bf(ld[icg + j][pix]);
#pragma unroll
    for (int j = 0; j < 8; j++) o1[j] = f2bf(ld[icg + 8 + j][pix]);
    unsigned short* dst = Ts + b * 147456 + (p0 + pix) * 64 + icg;
    *(u16x8*)dst = o0;
    *(u16x8*)(dst + 8) = o1;
  } else {
    // weight pack [oc][ic][3][3] -> [conv][tap][oc][ic]
    int idx = (bx - 432) * 256 + tid;   // 0..73727
    int conv = idx / 36864;
    int r = idx - conv * 36864;
    int tap = r >> 12;
    int r2 = r & 4095;
    int oc = r2 >> 6, ic = r2 & 63;
    const float* W = conv ? WC : WB;
    Wp[idx] = f2bf(W[oc * 576 + ic * 9 + tap]);
  }
}

// ================== conv3x3 as 9-tap implicit GEMM (MFMA) ===================
// Output pre-scaled by 1/sqrt(48) (consumed only by SA).
__global__ __launch_bounds__(256) void conv_mfma_kernel(
    const unsigned short* __restrict__ Ts, const unsigned short* __restrict__ Wp,
    const float* __restrict__ bB, const float* __restrict__ bC,
    unsigned short* __restrict__ Ab, unsigned short* __restrict__ Ac) {
  int b = blockIdx.y;
  int ptile = blockIdx.x;            // 0..143, 16 pixels each
  int tid = threadIdx.x;
  int wave = tid >> 6, lane = tid & 63;
  int conv = wave & 1;               // 0=B, 1=C
  int ochalf = wave >> 1;            // oc base = ochalf*32
  int lrow = lane & 15, kblk = lane >> 4;
  int p = ptile * 16 + lrow;         // this lane's A row (pixel)
  int y = p / 48, x = p - y * 48;
  const unsigned short* Tb = Ts + b * 147456;
  const unsigned short* Wc = Wp + conv * 36864;
  const short8 zz = {0, 0, 0, 0, 0, 0, 0, 0};
  f32x4 acc0 = {0.f, 0.f, 0.f, 0.f}, acc1 = {0.f, 0.f, 0.f, 0.f};
#pragma unroll
  for (int t = 0; t < 9; t++) {
    const int dy = t / 3 - 1, dx = t % 3 - 1;
    int yy = y + dy, xx = x + dx;
    bool valid = ((unsigned)yy < 48u) && ((unsigned)xx < 48u);
    int spix = valid ? (p + dy * 48 + dx) : p;
    const unsigned short* ap = Tb + spix * 64 + kblk * 8;
    short8 a0 = *(const short8*)ap;
    short8 a1 = *(const short8*)(ap + 32);
    if (!valid) { a0 = zz; a1 = zz; }
    const unsigned short* wp0 = Wc + (t * 64 + ochalf * 32 + lrow) * 64 + kblk * 8;
    short8 b00 = *(const short8*)wp0;
    short8 b01 = *(const short8*)(wp0 + 32);
    short8 b10 = *(const short8*)(wp0 + 1024);        // +16 oc rows
    short8 b11 = *(const short8*)(wp0 + 1024 + 32);
    acc0 = __builtin_amdgcn_mfma_f32_16x16x32_bf16(a0, b00, acc0, 0, 0, 0);
    acc0 = __builtin_amdgcn_mfma_f32_16x16x32_bf16(a1, b01, acc0, 0, 0, 0);
    acc1 = __builtin_amdgcn_mfma_f32_16x16x32_bf16(a0, b10, acc1, 0, 0, 0);
    acc1 = __builtin_amdgcn_mfma_f32_16x16x32_bf16(a1, b11, acc1, 0, 0, 0);
  }
  const float* bias = conv ? bC : bB;
  unsigned short* dst = conv ? Ac : Ab;
  int oc0 = ochalf * 32 + lrow;
  int oc1 = oc0 + 16;
  float bi0 = bias[oc0], bi1 = bias[oc1];
  int pixb = ptile * 16 + kblk * 4;
  u16x4 o0, o1;
#pragma unroll
  for (int i = 0; i < 4; i++) {
    o0[i] = f2bf((acc0[i] + bi0) * INV_SQRT48);
    o1[i] = f2bf((acc1[i] + bi1) * INV_SQRT48);
  }
  *(u16x4*)(dst + b * 147456 + oc0 * 2304 + pixb) = o0;
  *(u16x4*)(dst + b * 147456 + oc1 * 2304 + pixb) = o1;
}

// ========= SA phase 1: LDS-staged (global_load_lds) MFMA + row stats ========
// R7 config (best measured): block = 64 rows x 288-col chunk (z of 8),
// 9 stages of 32 cols, double-buffered global_load_lds, pre-swizzled source
// + XOR'd ds_read. Grid 36x4x8 = 1152 blocks.
__global__ __launch_bounds__(256) void sa_partial_kernel(
    const unsigned short* __restrict__ T16, const unsigned short* __restrict__ Ab16,
    const unsigned short* __restrict__ Ac16, float* __restrict__ rowstats) {
  __shared__ __align__(16) unsigned short lbuf[2][2][2048];  // [buf][T/Ac][32x64] 16KB
  int b = blockIdx.y, zc = blockIdx.z;
  int r0 = blockIdx.x * 64;
  const unsigned short* Tb = T16 + b * 147456;
  const unsigned short* Abb = Ab16 + b * 147456;
  const unsigned short* Acb = Ac16 + b * 147456;
  int tid = threadIdx.x, wave = tid >> 6, lane = tid & 63;
  int lrow = lane & 15, kblk = lane >> 4;
  int grow_base = r0 + wave * 16;
  // loop-invariant row-side fragments (registers)
  const short8 at0 = *(const short8*)(Tb + (grow_base + lrow) * 64 + kblk * 8);
  const short8 at1 = *(const short8*)(Tb + (grow_base + lrow) * 64 + 32 + kblk * 8);
  const short8 ar0 = *(const short8*)(Abb + (grow_base + lrow) * 64 + kblk * 8);
  const short8 ar1 = *(const short8*)(Abb + (grow_base + lrow) * 64 + 32 + kblk * 8);
  // staging role: waves 0,1 stage T halves; waves 2,3 stage Ac halves
  const unsigned short* sarr = (wave & 2) ? Acb : Tb;
  int aw = wave >> 1, hw = wave & 1;

  float Sx[4] = {0.f, 0.f, 0.f, 0.f}, Sa[4] = {0.f, 0.f, 0.f, 0.f};
  float Sa2[4] = {0.f, 0.f, 0.f, 0.f}, Zb[4] = {0.f, 0.f, 0.f, 0.f};
  float Qq[4] = {0.f, 0.f, 0.f, 0.f}, Ww[4] = {0.f, 0.f, 0.f, 0.f};

#define SA_STAGE(s_, p_)                                                        \
  {                                                                             \
    int n0_ = zc * 288 + (s_) * 32;                                             \
    const char* gb_ = (const char*)(sarr + n0_ * 64);                           \
    char* lb_ = (char*)(&lbuf[(p_)][aw][0]);                                    \
    _Pragma("unroll")                                                           \
    for (int j_ = 0; j_ < 2; j_++) {                                            \
      int d_ = hw * 2048 + j_ * 1024 + lane * 16;                               \
      int g_ = d_ ^ (((d_ >> 7) & 7) << 4);                                     \
      __builtin_amdgcn_global_load_lds(                                         \
          (const __attribute__((address_space(1))) unsigned int*)(gb_ + g_),    \
          (__attribute__((address_space(3))) unsigned int*)(lb_ + hw * 2048 + j_ * 1024), \
          16, 0, 0);                                                            \
    }                                                                           \
  }

  SA_STAGE(0, 0);
  __syncthreads();               // compiler drains vmcnt before barrier
  for (int s = 0; s < 9; s++) {
    int p = s & 1;
    if (s < 8) SA_STAGE(s + 1, p ^ 1);   // async prefetch into other buffer
    int n0 = zc * 288 + s * 32;
    const char* lbT = (const char*)&lbuf[p][0][0];
    const char* lbC = (const char*)&lbuf[p][1][0];
    int sw = (lrow & 7) << 4;
#pragma unroll
    for (int ctl = 0; ctl < 2; ctl++) {
      int abase = (ctl * 16 + lrow) * 128 + kblk * 16;
      short8 bt0 = *(const short8*)(lbT + (abase ^ sw));
      short8 bt1 = *(const short8*)(lbT + ((abase + 64) ^ sw));
      short8 bc0 = *(const short8*)(lbC + (abase ^ sw));
      short8 bc1 = *(const short8*)(lbC + ((abase + 64) ^ sw));
      f32x4 accA = {0.f, 0.f, 0.f, 0.f}, accV = {0.f, 0.f, 0.f, 0.f};
      accA = __builtin_amdgcn_mfma_f32_16x16x32_bf16(at0, bt0, accA, 0, 0, 0);
      accA = __builtin_amdgcn_mfma_f32_16x16x32_bf16(at1, bt1, accA, 0, 0, 0);
      accV = __builtin_amdgcn_mfma_f32_16x16x32_bf16(ar0, bc0, accV, 0, 0, 0);
      accV = __builtin_amdgcn_mfma_f32_16x16x32_bf16(ar1, bc1, accV, 0, 0, 0);
      int col = n0 + ctl * 16 + lrow;
#pragma unroll
      for (int i = 0; i < 4; i++) {
        int row = grow_base + kblk * 4 + i;
        float a = accA[i];
        float v = accV[i];
        if (row == col) { a = 0.f; v = 0.f; }
        float ea = __expf(a), eb = __expf(v);
        Sx[i] += ea; Sa[i] += a; Sa2[i] += a * a;
        Zb[i] += eb; Qq[i] += eb * eb; Ww[i] += a * eb;
      }
    }
    __syncthreads();             // next buffer staged; current free for reuse
  }
  // butterfly over the 16 column-lanes of each kblk group
#pragma unroll
  for (int m = 1; m < 16; m <<= 1) {
#pragma unroll
    for (int i = 0; i < 4; i++) {
      Sx[i] += __shfl_xor(Sx[i], m);
      Sa[i] += __shfl_xor(Sa[i], m);
      Sa2[i] += __shfl_xor(Sa2[i], m);
      Zb[i] += __shfl_xor(Zb[i], m);
      Qq[i] += __shfl_xor(Qq[i], m);
      Ww[i] += __shfl_xor(Ww[i], m);
    }
  }
  if (lrow == 0) {
#pragma unroll
    for (int i = 0; i < 4; i++) {
      float* rp = &rowstats[(b * 2304 + grow_base + kblk * 4 + i) * 6];
      atomicAdd(rp + 0, Sx[i]);
      atomicAdd(rp + 1, Sa[i]);
      atomicAdd(rp + 2, Sa2[i]);
      atomicAdd(rp + 3, Zb[i]);
      atomicAdd(rp + 4, Qq[i]);
      atomicAdd(rp + 5, Ww[i]);
    }
  }
#undef SA_STAGE
}

// ========= SA phase 2: rowloss from full stats, reduce to acc[1] ============
__global__ __launch_bounds__(256) void sa_final_kernel(
    const float* __restrict__ rowstats, float* __restrict__ acc) {
  int row = blockIdx.x * 256 + threadIdx.x;   // 0..9215
  const float* st = rowstats + row * 6;
  float vSx = st[0], vSa = st[1], vSa2 = st[2];
  float vZb = st[3], vQq = st[4], vWw = st[5];
  float L = __logf(vSx);
  float rl = vSa2 - 2.f * L * vSa + 2304.f * L * L + 2.f * L
             - 2.f * (vWw / vZb) + vQq / (vZb * vZb);
  __shared__ float red[4];
#pragma unroll
  for (int m = 1; m < 64; m <<= 1) rl += __shfl_xor(rl, m);
  if ((threadIdx.x & 63) == 0) red[threadIdx.x >> 6] = rl;
  __syncthreads();
  if (threadIdx.x == 0)
    atomicAdd(&acc[1], red[0] + red[1] + red[2] + red[3]);
}

// ============================ pa: maxpool 12x12 =============================
__global__ __launch_bounds__(256) void pool_kernel(
    const float* __restrict__ t4, const float* __restrict__ s4,
    float* __restrict__ pooled_t, float* __restrict__ pooled_s) {
  int widx = blockIdx.x * 4 + (threadIdx.x >> 6);  // 0..2047
  int lane = threadIdx.x & 63;
  int p = widx & 3, bc = widx >> 2;
  int py = p >> 1, px = p & 1;
  int base = bc * 576 + py * 288 + px * 12;
  float mt = -1e30f, ms = -1e30f;
  for (int e = lane; e < 144; e += 64) {
    int iy = e / 12, ix = e - iy * 12;
    int off = base + iy * 24 + ix;
    mt = fmaxf(mt, t4[off]);
    ms = fmaxf(ms, s4[off]);
  }
#pragma unroll
  for (int d = 1; d < 64; d <<= 1) {
    mt = fmaxf(mt, __shfl_xor(mt, d));
    ms = fmaxf(ms, __shfl_xor(ms, d));
  }
  if (lane == 0) { pooled_t[widx] = mt; pooled_s[widx] = ms; }
}

__global__ __launch_bounds__(256) void pa_final_kernel(
    const float* __restrict__ pooled_t, const float* __restrict__ pooled_s,
    float* __restrict__ acc) {
  __shared__ float ps[2048], pt[2048], nrm[32], sim[128];
  int tid = threadIdx.x;
  for (int q = tid; q < 2048; q += 256) { ps[q] = pooled_s[q]; pt[q] = pooled_t[q]; }
  __syncthreads();
  if (tid < 32) {
    int tens = tid >> 4, r = tid & 15, b = r >> 2, p = r & 3;
    const float* v = tens ? pt : ps;
    float s = 0.f;
    for (int c = 0; c < 128; c++) { float x = v[(b * 128 + c) * 4 + p]; s += x * x; }
    nrm[tid] = sqrtf(s) + 1e-8f;
  }
  __syncthreads();
  if (tid < 128) {
    int tens = tid >> 6, r = tid & 63, b = r >> 4, m = (r >> 2) & 3, n = r & 3;
    const float* v = tens ? pt : ps;
    float s = 0.f;
    for (int c = 0; c < 128; c++)
      s += v[(b * 128 + c) * 4 + m] * v[(b * 128 + c) * 4 + n];
    sim[tid] = s / (nrm[tens * 16 + b * 4 + m] * nrm[tens * 16 + b * 4 + n]);
  }
  __syncthreads();
  if (tid < 64) {
    float df = sim[64 + tid] - sim[tid];
    float d = df * df;
#pragma unroll
    for (int k = 1; k < 64; k <<= 1) d += __shfl_xor(d, k);
    if (tid == 0) acc[4] = d;   // raw; finalize /64
  }
}

// ================================ pi (KL) ===================================
__global__ __launch_bounds__(256) void pi_kernel(
    const float* __restrict__ t_out, const float* __restrict__ s_out,
    float* __restrict__ acc) {
  int idx = blockIdx.x * 256 + threadIdx.x;  // 0..65535
  int b = idx >> 14, rem = idx & 16383;
  const float* tp = t_out + b * 344064 + rem;
  const float* sp = s_out + b * 344064 + rem;
  float t[21], s[21];
#pragma unroll
  for (int c = 0; c < 21; c++) { t[c] = tp[c * 16384]; s[c] = sp[c * 16384]; }
  float mt = t[0], ms = s[0];
#pragma unroll
  for (int c = 1; c < 21; c++) { mt = fmaxf(mt, t[c]); ms = fmaxf(ms, s[c]); }
  float Zt = 0.f, Zs = 0.f;
#pragma unroll
  for (int c = 0; c < 21; c++) { Zt += __expf(t[c] - mt); Zs += __expf(s[c] - ms); }
  float lt = __logf(Zt), ls = __logf(Zs);
  float sum = 0.f;
#pragma unroll
  for (int c = 0; c < 21; c++) {
    float lq = t[c] - mt - lt;
    float lp = s[c] - ms - ls;
    sum += __expf(lq) * (lq - lp);
  }
  __shared__ float red[4];
#pragma unroll
  for (int k = 1; k < 64; k <<= 1) sum += __shfl_xor(sum, k);
  if ((threadIdx.x & 63) == 0) red[threadIdx.x >> 6] = sum;
  __syncthreads();
  if (threadIdx.x == 0) atomicAdd(&acc[0], red[0] + red[1] + red[2] + red[3]);
}

// ========== unified MFMA 21x21 grams: ic (raw) + lo cross (P=softmax) =======
// grid (32 k-chunks of 512, 16 jobs); each wave: one 128-k slab.
#define GR_PAD 136
__global__ __launch_bounds__(256) void gram_mfma_kernel(
    const float* __restrict__ s_out, const float* __restrict__ t_out,
    const float* __restrict__ zrbuf, float* __restrict__ Gs,
    float* __restrict__ Gt, float* __restrict__ cross) {
  __shared__ unsigned short st[4][32][GR_PAD];   // 34816 B; aliased as red later
  int job = blockIdx.y;
  int kind = job >> 3, tens = (job >> 2) & 1, b = job & 3;
  const float* x = (tens ? t_out : s_out) + b * 344064;
  const float* zr = zrbuf + ((tens * 4 + b) * 21) * 128;
  int tid = threadIdx.x, wave = tid >> 6, lane = tid & 63;
  int lrow = lane & 15, kblk = lane >> 4;
#pragma unroll
  for (int r = 21; r < 32; r++)
    *(unsigned int*)&st[wave][r][lane * 2] = 0u;
  f32x4 a00 = {0.f, 0.f, 0.f, 0.f}, a01 = {0.f, 0.f, 0.f, 0.f};
  f32x4 a11 = {0.f, 0.f, 0.f, 0.f};
  int k0 = blockIdx.x * 512 + wave * 128;
  for (int c = 0; c < 21; c++) {
    float2 v = *(const float2*)(x + c * 16384 + k0 + lane * 2);
    if (kind) {
      float2 z2 = *(const float2*)(zr + c * 128 + ((lane * 2) & 127));
      v.x = __expf(v.x) * z2.x;
      v.y = __expf(v.y) * z2.y;
    }
    unsigned int pk = (unsigned int)f2bf(v.x) | ((unsigned int)f2bf(v.y) << 16);
    *(unsigned int*)&st[wave][c][lane * 2] = pk;
  }
#pragma unroll
  for (int kk = 0; kk < 4; kk++) {
    short8 A0 = *(const short8*)&st[wave][lrow][kk * 32 + kblk * 8];
    short8 A1 = *(const short8*)&st[wave][16 + lrow][kk * 32 + kblk * 8];
    a00 = __builtin_amdgcn_mfma_f32_16x16x32_bf16(A0, A0, a00, 0, 0, 0);
    a01 = __builtin_amdgcn_mfma_f32_16x16x32_bf16(A0, A1, a01, 0, 0, 0);
    a11 = __builtin_amdgcn_mfma_f32_16x16x32_bf16(A1, A1, a11, 0, 0, 0);
  }
  __syncthreads();
  float* red = (float*)&st[0][0][0];   // [4][3][16][16]
#pragma unroll
  for (int i = 0; i < 4; i++) {
    int m = kblk * 4 + i;
    red[((wave * 3 + 0) * 16 + m) * 16 + lrow] = a00[i];
    red[((wave * 3 + 1) * 16 + m) * 16 + lrow] = a01[i];
    red[((wave * 3 + 2) * 16 + m) * 16 + lrow] = a11[i];
  }
  __syncthreads();
  if (tid < 441) {
    int i = tid / 21, j = tid - i * 21;
    float s = 0.f;
#pragma unroll
    for (int w = 0; w < 4; w++) {
      float v;
      if (i < 16)
        v = (j < 16) ? red[((w * 3 + 0) * 16 + i) * 16 + j]
                     : red[((w * 3 + 1) * 16 + i) * 16 + (j - 16)];
      else
        v = (j < 16) ? red[((w * 3 + 1) * 16 + j) * 16 + (i - 16)]
                     : red[((w * 3 + 2) * 16 + (i - 16)) * 16 + (j - 16)];
      s += v;
    }
    float* dst = kind ? (cross + tens * 441) : ((tens ? Gt : Gs) + b * 441);
    atomicAdd(&dst[i * 21 + j], s);
  }
}

// ============================ lo stats (zr + self-ent) ======================
// 256 threads: w = tid&127, half = tid>>7 covers h in [half*64, half*64+64).
__global__ __launch_bounds__(256) void lo_stats_kernel(
    const float* __restrict__ s_out, const float* __restrict__ t_out,
    float* __restrict__ zrbuf, float* __restrict__ self_ent) {
  int c = blockIdx.x, b = blockIdx.y, tens = blockIdx.z;
  const float* x = (tens ? t_out : s_out) + b * 344064 + c * 16384;
  int tid = threadIdx.x;
  int w = tid & 127, half = tid >> 7;
  float Z = 0.f, U = 0.f;
  int h0 = half * 64;
#pragma unroll 4
  for (int h = h0; h < h0 + 64; h++) {
    float v = x[h * 128 + w];
    float e = __expf(v);
    Z += e; U += v * e;
  }
  __shared__ float zs[128], us[128], r2[2];
  if (half) { zs[w] = Z; us[w] = U; }
  __syncthreads();
  if (!half) {
    Z += zs[w]; U += us[w];
    int idx = ((tens * 4 + b) * 21 + c) * 128 + w;
    zrbuf[idx] = 1.0f / Z;
    float se = U / Z - __logf(Z);
#pragma unroll
    for (int k = 1; k < 64; k <<= 1) se += __shfl_xor(se, k);
    if ((tid & 63) == 0) r2[tid >> 6] = se;
  }
  __syncthreads();
  if (tid == 0) atomicAdd(&self_ent[tens * 21 + c], r2[0] + r2[1]);
}

// ======== fused final: ic norm-diff + lo norm-diff + output scalars =========
__global__ __launch_bounds__(512) void final_kernel(
    const float* __restrict__ Gs, const float* __restrict__ Gt,
    const float* __restrict__ self_ent, const float* __restrict__ cross,
    const float* __restrict__ acc, float* __restrict__ out) {
  __shared__ float gs[441], gt[441], ns[21], nt_[21], rd[8];
  __shared__ float icv, lov;
  int tid = threadIdx.x;
  // ---- ic ----
  float total = 0.f;
  for (int b = 0; b < 4; b++) {
    __syncthreads();
    if (tid < 441) { gs[tid] = Gs[b * 441 + tid]; gt[tid] = Gt[b * 441 + tid]; }
    __syncthreads();
    if (tid < 21) {
      float a = 0.f, c2 = 0.f;
      for (int j = 0; j < 21; j++) {
        a += gs[tid * 21 + j] * gs[tid * 21 + j];
        c2 += gt[tid * 21 + j] * gt[tid * 21 + j];
      }
      ns[tid] = fmaxf(sqrtf(a), 1e-12f);
      nt_[tid] = fmaxf(sqrtf(c2), 1e-12f);
    }
    __syncthreads();
    if (tid < 441) {
      int i = tid / 21;
      float d = gs[tid] / ns[i] - gt[tid] / nt_[i];
      total += d * d;
    }
  }
#pragma unroll
  for (int k = 1; k < 64; k <<= 1) total += __shfl_xor(total, k);
  if ((tid & 63) == 0) rd[tid >> 6] = total;
  __syncthreads();
  if (tid == 0) {
    float s = 0.f;
    for (int i = 0; i < 8; i++) s += rd[i];
    icv = s;
  }
  __syncthreads();
  // ---- lo (reuse gs/gt as Ks/Kt) ----
  if (tid < 441) {
    int i = tid / 21, j = tid - i * 21;
    int mx_ = i > j ? i : j;
    gs[tid] = (self_ent[mx_] - cross[tid]) * 0.25f;
    gt[tid] = (self_ent[21 + mx_] - cross[441 + tid]) * 0.25f;
  }
  __syncthreads();
  if (tid < 21) {
    float a = 0.f, b2 = 0.f;
    for (int j = 0; j < 21; j++) {
      a += gs[tid * 21 + j] * gs[tid * 21 + j];
      b2 += gt[tid * 21 + j] * gt[tid * 21 + j];
    }
    ns[tid] = fmaxf(sqrtf(a), 1e-12f);
    nt_[tid] = fmaxf(sqrtf(b2), 1e-12f);
  }
  __syncthreads();
  float tot = 0.f;
  if (tid < 441) {
    int i = tid / 21;
    float d = gs[tid] / ns[i] - gt[tid] / nt_[i];
    tot = d * d;
  }
#pragma unroll
  for (int k = 1; k < 64; k <<= 1) tot += __shfl_xor(tot, k);
  if ((tid & 63) == 0) rd[tid >> 6] = tot;
  __syncthreads();
  if (tid == 0) {
    float s = 0.f;
    for (int i = 0; i < 8; i++) s += rd[i];
    lov = s;
    out[0] = acc[4] * (1.0f / 64.0f);                 // pa_loss
    out[1] = acc[0] * (1.0f / 1376256.0f);            // pi_loss
    out[2] = icv * (1.0f / 84.0f);                    // ic_loss
    out[3] = lov * (1.0f / 1764.0f);                  // lo_loss
    out[4] = sqrtf(acc[1]) * (1.0f / 21233664.0f);    // SA_loss (4*2304^2)
  }
}

// ============================================================================
extern "C" void kernel_launch(void* const* d_in, const int* in_sizes, int n_in,
                              void* d_out, int out_size, void* d_ws, size_t ws_size,
                              hipStream_t stream) {
  const float* t3 = (const float*)d_in[0];
  const float* s3 = (const float*)d_in[1];
  const float* t4 = (const float*)d_in[2];
  const float* s4 = (const float*)d_in[3];
  const float* t_out = (const float*)d_in[4];
  const float* s_out = (const float*)d_in[5];
  const float* WB = (const float*)d_in[6];
  const float* bB = (const float*)d_in[7];
  const float* WC = (const float*)d_in[8];
  const float* bC = (const float*)d_in[9];
  float* out = (float*)d_out;
  float* ws = (float*)d_ws;

  float* acc = ws;                           // 8
  float* self_ent = ws + 8;                  // 42  -> 50
  float* cross = ws + 50;                    // 882 -> 932
  float* Gs = ws + 932;                      // 1764 -> 2696
  float* Gt = ws + 2696;                     // 1764 -> 4460
  float* rowstats = ws + 4460;               // 55296 -> 59756 (zeroed region end)
  float* pooled_s = ws + 59756;              // 2048 -> 61804
  float* pooled_t = ws + 61804;              // 2048 -> 63852
  float* zrbuf = ws + 63852;                 // 21504 -> 85356
  unsigned short* T16u = (unsigned short*)(ws + 85356);    // 589824 bf16
  unsigned short* Ab16u = (unsigned short*)(ws + 380268);  // 589824 bf16
  unsigned short* Ac16u = (unsigned short*)(ws + 675180);  // 589824 bf16
  unsigned short* Ts16u = (unsigned short*)(ws + 970092);  // 589824 bf16
  unsigned short* Wp16u = (unsigned short*)(ws + 1265004); // 73728 bf16

  hipMemsetAsync(ws, 0, 59756 * sizeof(float), stream);
  hipMemcpyAsync(d_out, (const void*)s_out, 1376256 * sizeof(float),
                 hipMemcpyDeviceToDevice, stream);

  prep_kernel<<<720, 256, 0, stream>>>(t3, s3, WB, WC, T16u, Ts16u, Wp16u);
  conv_mfma_kernel<<<dim3(144, 4), 256, 0, stream>>>(Ts16u, Wp16u, bB, bC, Ab16u, Ac16u);
  sa_partial_kernel<<<dim3(36, 4, 8), 256, 0, stream>>>(T16u, Ab16u, Ac16u, rowstats);
  sa_final_kernel<<<36, 256, 0, stream>>>(rowstats, acc);
  pool_kernel<<<512, 256, 0, stream>>>(t4, s4, pooled_t, pooled_s);
  pa_final_kernel<<<1, 256, 0, stream>>>(pooled_t, pooled_s, acc);
  pi_kernel<<<256, 256, 0, stream>>>(t_out, s_out, acc);
  lo_stats_kernel<<<dim3(21, 4, 2), 256, 0, stream>>>(s_out, t_out, zrbuf, self_ent);
  gram_mfma_kernel<<<dim3(32, 16), 256, 0, stream>>>(s_out, t_out, zrbuf, Gs, Gt, cross);
  final_kernel<<<1, 512, 0, stream>>>(Gs, Gt, self_ent, cross, acc, out + 1376256);
}

// Round 10
// 101.224 us; speedup vs baseline: 1.6032x; 1.1317x over previous
//
#include <hip/hip_runtime.h>
#include <math.h>

// ---------------------------------------------------------------------------
// Shapes:
// t_feat3/s_feat3: [4][64][48][48]  (147456 per batch) -> viewed flat [2304][64]
// t_feat4/s_feat4: [4][128][24][24]
// t_out/s_out:     [4][21][128][128] (344064 per batch, 16384 per class)
// W_B/W_C: [64][64][3][3], b_B/b_C: [64]
// Output: s_out copy (1376256 floats) then pa, pi, ic, lo, SA scalars.
// ---------------------------------------------------------------------------

typedef __attribute__((ext_vector_type(8))) short short8;   // 8 bf16 (4 VGPR)
typedef __attribute__((ext_vector_type(4))) float f32x4;
typedef __attribute__((ext_vector_type(8))) unsigned short u16x8;
typedef __attribute__((ext_vector_type(4))) unsigned short u16x4;

#define INV_SQRT48 0.14433756729740643f

static __device__ __forceinline__ unsigned short f2bf(float x) {
  unsigned int u = __float_as_uint(x);
  unsigned int r = (u + 0x7fffu + ((u >> 16) & 1u)) >> 16;
  return (unsigned short)r;
}

// ===== fused preprocessing: cvt (288 blk) | transpose (144) | pack_w (288) ==
__global__ __launch_bounds__(256) void prep_kernel(
    const float* __restrict__ t3, const float* __restrict__ s3,
    const float* __restrict__ WB, const float* __restrict__ WC,
    unsigned short* __restrict__ T16, unsigned short* __restrict__ Ts,
    unsigned short* __restrict__ Wp) {
  __shared__ float ld[64][65];
  int bx = blockIdx.x;
  int tid = threadIdx.x;
  if (bx < 288) {
    // t3 -> bf16 pre-scaled by 1/sqrt(48)
    int i = (bx * 256 + tid) * 8;
    float4 a = *(const float4*)(t3 + i);
    float4 b = *(const float4*)(t3 + i + 4);
    u16x8 v;
    v[0] = f2bf(a.x * INV_SQRT48); v[1] = f2bf(a.y * INV_SQRT48);
    v[2] = f2bf(a.z * INV_SQRT48); v[3] = f2bf(a.w * INV_SQRT48);
    v[4] = f2bf(b.x * INV_SQRT48); v[5] = f2bf(b.y * INV_SQRT48);
    v[6] = f2bf(b.z * INV_SQRT48); v[7] = f2bf(b.w * INV_SQRT48);
    *(u16x8*)(T16 + i) = v;
  } else if (bx < 432) {
    // s3 -> transposed bf16 [b][pix][ic]
    int t = bx - 288;
    int b = t / 36;
    int p0 = (t - b * 36) * 64;
    const float* src = s3 + b * 147456;
#pragma unroll
    for (int q = tid; q < 1024; q += 256) {
      int ic = q >> 4; int px = (q & 15) << 2;
      float4 v = *(const float4*)(src + ic * 2304 + p0 + px);
      ld[ic][px] = v.x; ld[ic][px + 1] = v.y; ld[ic][px + 2] = v.z; ld[ic][px + 3] = v.w;
    }
    __syncthreads();
    int pix = tid >> 2, icg = (tid & 3) * 16;
    u16x8 o0, o1;
#pragma unroll
    for (int j = 0; j < 8; j++) o0[j] = f2bf(ld[icg + j][pix]);
#pragma unroll
    for (int j = 0; j < 8; j++) o1[j] = f2bf(ld[icg + 8 + j][pix]);
    unsigned short* dst = Ts + b * 147456 + (p0 + pix) * 64 + icg;
    *(u16x8*)dst = o0;
    *(u16x8*)(dst + 8) = o1;
  } else {
    // weight pack [oc][ic][3][3] -> [conv][tap][oc][ic]
    int idx = (bx - 432) * 256 + tid;   // 0..73727
    int conv = idx / 36864;
    int r = idx - conv * 36864;
    int tap = r >> 12;
    int r2 = r & 4095;
    int oc = r2 >> 6, ic = r2 & 63;
    const float* W = conv ? WC : WB;
    Wp[idx] = f2bf(W[oc * 576 + ic * 9 + tap]);
  }
}

// ================== conv3x3 as 9-tap implicit GEMM (MFMA) ===================
// Output pre-scaled by 1/sqrt(48) (consumed only by SA).
__global__ __launch_bounds__(256) void conv_mfma_kernel(
    const unsigned short* __restrict__ Ts, const unsigned short* __restrict__ Wp,
    const float* __restrict__ bB, const float* __restrict__ bC,
    unsigned short* __restrict__ Ab, unsigned short* __restrict__ Ac) {
  int b = blockIdx.y;
  int ptile = blockIdx.x;            // 0..143, 16 pixels each
  int tid = threadIdx.x;
  int wave = tid >> 6, lane = tid & 63;
  int conv = wave & 1;               // 0=B, 1=C
  int ochalf = wave >> 1;            // oc base = ochalf*32
  int lrow = lane & 15, kblk = lane >> 4;
  int p = ptile * 16 + lrow;         // this lane's A row (pixel)
  int y = p / 48, x = p - y * 48;
  const unsigned short* Tb = Ts + b * 147456;
  const unsigned short* Wc = Wp + conv * 36864;
  const short8 zz = {0, 0, 0, 0, 0, 0, 0, 0};
  f32x4 acc0 = {0.f, 0.f, 0.f, 0.f}, acc1 = {0.f, 0.f, 0.f, 0.f};
#pragma unroll
  for (int t = 0; t < 9; t++) {
    const int dy = t / 3 - 1, dx = t % 3 - 1;
    int yy = y + dy, xx = x + dx;
    bool valid = ((unsigned)yy < 48u) && ((unsigned)xx < 48u);
    int spix = valid ? (p + dy * 48 + dx) : p;
    const unsigned short* ap = Tb + spix * 64 + kblk * 8;
    short8 a0 = *(const short8*)ap;
    short8 a1 = *(const short8*)(ap + 32);
    if (!valid) { a0 = zz; a1 = zz; }
    const unsigned short* wp0 = Wc + (t * 64 + ochalf * 32 + lrow) * 64 + kblk * 8;
    short8 b00 = *(const short8*)wp0;
    short8 b01 = *(const short8*)(wp0 + 32);
    short8 b10 = *(const short8*)(wp0 + 1024);        // +16 oc rows
    short8 b11 = *(const short8*)(wp0 + 1024 + 32);
    acc0 = __builtin_amdgcn_mfma_f32_16x16x32_bf16(a0, b00, acc0, 0, 0, 0);
    acc0 = __builtin_amdgcn_mfma_f32_16x16x32_bf16(a1, b01, acc0, 0, 0, 0);
    acc1 = __builtin_amdgcn_mfma_f32_16x16x32_bf16(a0, b10, acc1, 0, 0, 0);
    acc1 = __builtin_amdgcn_mfma_f32_16x16x32_bf16(a1, b11, acc1, 0, 0, 0);
  }
  const float* bias = conv ? bC : bB;
  unsigned short* dst = conv ? Ac : Ab;
  int oc0 = ochalf * 32 + lrow;
  int oc1 = oc0 + 16;
  float bi0 = bias[oc0], bi1 = bias[oc1];
  int pixb = ptile * 16 + kblk * 4;
  u16x4 o0, o1;
#pragma unroll
  for (int i = 0; i < 4; i++) {
    o0[i] = f2bf((acc0[i] + bi0) * INV_SQRT48);
    o1[i] = f2bf((acc1[i] + bi1) * INV_SQRT48);
  }
  *(u16x4*)(dst + b * 147456 + oc0 * 2304 + pixb) = o0;
  *(u16x4*)(dst + b * 147456 + oc1 * 2304 + pixb) = o1;
}

// ========= SA phase 1: counted-vmcnt 3-buffer pipeline (T3/T4) ==============
// Block: 64 rows x 288-col chunk. 9 stages of 32 cols; depth-2 prefetch,
// raw s_barrier + s_waitcnt vmcnt(2) (loads stay in flight across barriers;
// never drained to 0 mid-loop). Partials -> plain stores (no atomics).
__global__ __launch_bounds__(256) void sa_partial_kernel(
    const unsigned short* __restrict__ T16, const unsigned short* __restrict__ Ab16,
    const unsigned short* __restrict__ Ac16, float* __restrict__ rowstats2) {
  __shared__ __align__(16) unsigned short lbuf[3][2][2048];  // 24 KB, 3 buffers
  int b = blockIdx.y, zc = blockIdx.z;
  int r0 = blockIdx.x * 64;
  const unsigned short* Tb = T16 + b * 147456;
  const unsigned short* Abb = Ab16 + b * 147456;
  const unsigned short* Acb = Ac16 + b * 147456;
  int tid = threadIdx.x, wave = tid >> 6, lane = tid & 63;
  int lrow = lane & 15, kblk = lane >> 4;
  int grow_base = r0 + wave * 16;
  // loop-invariant row-side fragments (registers)
  const short8 at0 = *(const short8*)(Tb + (grow_base + lrow) * 64 + kblk * 8);
  const short8 at1 = *(const short8*)(Tb + (grow_base + lrow) * 64 + 32 + kblk * 8);
  const short8 ar0 = *(const short8*)(Abb + (grow_base + lrow) * 64 + kblk * 8);
  const short8 ar1 = *(const short8*)(Abb + (grow_base + lrow) * 64 + 32 + kblk * 8);
  // staging role: waves 0,1 stage T halves; waves 2,3 stage Ac halves
  const unsigned short* sarr = (wave & 2) ? Acb : Tb;
  int aw = wave >> 1, hw = wave & 1;

  float Sx[4] = {0.f, 0.f, 0.f, 0.f}, Sa[4] = {0.f, 0.f, 0.f, 0.f};
  float Sa2[4] = {0.f, 0.f, 0.f, 0.f}, Zb[4] = {0.f, 0.f, 0.f, 0.f};
  float Qq[4] = {0.f, 0.f, 0.f, 0.f}, Ww[4] = {0.f, 0.f, 0.f, 0.f};

#define SA_STAGE(s_, p_)                                                        \
  {                                                                             \
    int n0_ = zc * 288 + (s_) * 32;                                             \
    const char* gb_ = (const char*)(sarr + n0_ * 64);                           \
    char* lb_ = (char*)(&lbuf[(p_)][aw][0]);                                    \
    _Pragma("unroll")                                                           \
    for (int j_ = 0; j_ < 2; j_++) {                                            \
      int d_ = hw * 2048 + j_ * 1024 + lane * 16;                               \
      int g_ = d_ ^ (((d_ >> 7) & 7) << 4);                                     \
      __builtin_amdgcn_global_load_lds(                                         \
          (const __attribute__((address_space(1))) unsigned int*)(gb_ + g_),    \
          (__attribute__((address_space(3))) unsigned int*)(lb_ + hw * 2048 + j_ * 1024), \
          16, 0, 0);                                                            \
    }                                                                           \
  }

  SA_STAGE(0, 0);                      // 2 loads/wave in flight
  SA_STAGE(1, 1);                      // 4 in flight
#pragma unroll 1
  for (int s = 0; s < 9; s++) {
    // wait until only the NEXT stage's (and deeper) loads remain -> stage s landed
    if (s < 8) asm volatile("s_waitcnt vmcnt(2)" ::: "memory");
    else       asm volatile("s_waitcnt vmcnt(0)" ::: "memory");
    __builtin_amdgcn_sched_barrier(0);
    __builtin_amdgcn_s_barrier();      // all waves: stage s in LDS, stage s-1 reads done
    __builtin_amdgcn_sched_barrier(0);
    if (s + 2 <= 8) SA_STAGE(s + 2, (s + 2) % 3);   // overwrite buf[(s-1)%3] (safe)
    int p = s % 3;
    int n0 = zc * 288 + s * 32;
    const char* lbT = (const char*)&lbuf[p][0][0];
    const char* lbC = (const char*)&lbuf[p][1][0];
    int sw = (lrow & 7) << 4;
#pragma unroll
    for (int ctl = 0; ctl < 2; ctl++) {
      int abase = (ctl * 16 + lrow) * 128 + kblk * 16;
      short8 bt0 = *(const short8*)(lbT + (abase ^ sw));
      short8 bt1 = *(const short8*)(lbT + ((abase + 64) ^ sw));
      short8 bc0 = *(const short8*)(lbC + (abase ^ sw));
      short8 bc1 = *(const short8*)(lbC + ((abase + 64) ^ sw));
      f32x4 accA = {0.f, 0.f, 0.f, 0.f}, accV = {0.f, 0.f, 0.f, 0.f};
      accA = __builtin_amdgcn_mfma_f32_16x16x32_bf16(at0, bt0, accA, 0, 0, 0);
      accA = __builtin_amdgcn_mfma_f32_16x16x32_bf16(at1, bt1, accA, 0, 0, 0);
      accV = __builtin_amdgcn_mfma_f32_16x16x32_bf16(ar0, bc0, accV, 0, 0, 0);
      accV = __builtin_amdgcn_mfma_f32_16x16x32_bf16(ar1, bc1, accV, 0, 0, 0);
      int col = n0 + ctl * 16 + lrow;
#pragma unroll
      for (int i = 0; i < 4; i++) {
        int row = grow_base + kblk * 4 + i;
        float a = accA[i];
        float v = accV[i];
        if (row == col) { a = 0.f; v = 0.f; }
        float ea = __expf(a), eb = __expf(v);
        Sx[i] += ea; Sa[i] += a; Sa2[i] += a * a;
        Zb[i] += eb; Qq[i] += eb * eb; Ww[i] += a * eb;
      }
    }
  }
  // butterfly over the 16 column-lanes of each kblk group
#pragma unroll
  for (int m = 1; m < 16; m <<= 1) {
#pragma unroll
    for (int i = 0; i < 4; i++) {
      Sx[i] += __shfl_xor(Sx[i], m);
      Sa[i] += __shfl_xor(Sa[i], m);
      Sa2[i] += __shfl_xor(Sa2[i], m);
      Zb[i] += __shfl_xor(Zb[i], m);
      Qq[i] += __shfl_xor(Qq[i], m);
      Ww[i] += __shfl_xor(Ww[i], m);
    }
  }
  if (lrow == 0) {
    // plain stores (no atomics): rowstats2[zc][b*2304+row][6]
#pragma unroll
    for (int i = 0; i < 4; i++) {
      int row = grow_base + kblk * 4 + i;
      float* rp = &rowstats2[((size_t)zc * 9216 + b * 2304 + row) * 6];
      rp[0] = Sx[i]; rp[1] = Sa[i]; rp[2] = Sa2[i];
      rp[3] = Zb[i]; rp[4] = Qq[i]; rp[5] = Ww[i];
    }
  }
#undef SA_STAGE
}

// ========= SA phase 2: 8-way partial reduce + rowloss -> acc[1] =============
__global__ __launch_bounds__(256) void sa_final_kernel(
    const float* __restrict__ rowstats2, float* __restrict__ acc) {
  int row = blockIdx.x * 256 + threadIdx.x;   // 0..9215
  float st[6] = {0.f, 0.f, 0.f, 0.f, 0.f, 0.f};
#pragma unroll
  for (int z = 0; z < 8; z++) {
    const float* rp = rowstats2 + ((size_t)z * 9216 + row) * 6;
#pragma unroll
    for (int s = 0; s < 6; s++) st[s] += rp[s];
  }
  float L = __logf(st[0]);
  float rl = st[2] - 2.f * L * st[1] + 2304.f * L * L + 2.f * L
             - 2.f * (st[5] / st[3]) + st[4] / (st[3] * st[3]);
  __shared__ float red[4];
#pragma unroll
  for (int m = 1; m < 64; m <<= 1) rl += __shfl_xor(rl, m);
  if ((threadIdx.x & 63) == 0) red[threadIdx.x >> 6] = rl;
  __syncthreads();
  if (threadIdx.x == 0)
    atomicAdd(&acc[1], red[0] + red[1] + red[2] + red[3]);
}

// ============================ pa: maxpool 12x12 =============================
__global__ __launch_bounds__(256) void pool_kernel(
    const float* __restrict__ t4, const float* __restrict__ s4,
    float* __restrict__ pooled_t, float* __restrict__ pooled_s) {
  int widx = blockIdx.x * 4 + (threadIdx.x >> 6);  // 0..2047
  int lane = threadIdx.x & 63;
  int p = widx & 3, bc = widx >> 2;
  int py = p >> 1, px = p & 1;
  int base = bc * 576 + py * 288 + px * 12;
  float mt = -1e30f, ms = -1e30f;
  for (int e = lane; e < 144; e += 64) {
    int iy = e / 12, ix = e - iy * 12;
    int off = base + iy * 24 + ix;
    mt = fmaxf(mt, t4[off]);
    ms = fmaxf(ms, s4[off]);
  }
#pragma unroll
  for (int d = 1; d < 64; d <<= 1) {
    mt = fmaxf(mt, __shfl_xor(mt, d));
    ms = fmaxf(ms, __shfl_xor(ms, d));
  }
  if (lane == 0) { pooled_t[widx] = mt; pooled_s[widx] = ms; }
}

__global__ __launch_bounds__(256) void pa_final_kernel(
    const float* __restrict__ pooled_t, const float* __restrict__ pooled_s,
    float* __restrict__ acc) {
  __shared__ float ps[2048], pt[2048], nrm[32], sim[128];
  int tid = threadIdx.x;
  for (int q = tid; q < 2048; q += 256) { ps[q] = pooled_s[q]; pt[q] = pooled_t[q]; }
  __syncthreads();
  if (tid < 32) {
    int tens = tid >> 4, r = tid & 15, b = r >> 2, p = r & 3;
    const float* v = tens ? pt : ps;
    float s = 0.f;
    for (int c = 0; c < 128; c++) { float x = v[(b * 128 + c) * 4 + p]; s += x * x; }
    nrm[tid] = sqrtf(s) + 1e-8f;
  }
  __syncthreads();
  if (tid < 128) {
    int tens = tid >> 6, r = tid & 63, b = r >> 4, m = (r >> 2) & 3, n = r & 3;
    const float* v = tens ? pt : ps;
    float s = 0.f;
    for (int c = 0; c < 128; c++)
      s += v[(b * 128 + c) * 4 + m] * v[(b * 128 + c) * 4 + n];
    sim[tid] = s / (nrm[tens * 16 + b * 4 + m] * nrm[tens * 16 + b * 4 + n]);
  }
  __syncthreads();
  if (tid < 64) {
    float df = sim[64 + tid] - sim[tid];
    float d = df * df;
#pragma unroll
    for (int k = 1; k < 64; k <<= 1) d += __shfl_xor(d, k);
    if (tid == 0) acc[4] = d;   // raw; finalize /64
  }
}

// ================================ pi (KL) ===================================
__global__ __launch_bounds__(256) void pi_kernel(
    const float* __restrict__ t_out, const float* __restrict__ s_out,
    float* __restrict__ acc) {
  int idx = blockIdx.x * 256 + threadIdx.x;  // 0..65535
  int b = idx >> 14, rem = idx & 16383;
  const float* tp = t_out + b * 344064 + rem;
  const float* sp = s_out + b * 344064 + rem;
  float t[21], s[21];
#pragma unroll
  for (int c = 0; c < 21; c++) { t[c] = tp[c * 16384]; s[c] = sp[c * 16384]; }
  float mt = t[0], ms = s[0];
#pragma unroll
  for (int c = 1; c < 21; c++) { mt = fmaxf(mt, t[c]); ms = fmaxf(ms, s[c]); }
  float Zt = 0.f, Zs = 0.f;
#pragma unroll
  for (int c = 0; c < 21; c++) { Zt += __expf(t[c] - mt); Zs += __expf(s[c] - ms); }
  float lt = __logf(Zt), ls = __logf(Zs);
  float sum = 0.f;
#pragma unroll
  for (int c = 0; c < 21; c++) {
    float lq = t[c] - mt - lt;
    float lp = s[c] - ms - ls;
    sum += __expf(lq) * (lq - lp);
  }
  __shared__ float red[4];
#pragma unroll
  for (int k = 1; k < 64; k <<= 1) sum += __shfl_xor(sum, k);
  if ((threadIdx.x & 63) == 0) red[threadIdx.x >> 6] = sum;
  __syncthreads();
  if (threadIdx.x == 0) atomicAdd(&acc[0], red[0] + red[1] + red[2] + red[3]);
}

// ========== unified MFMA 21x21 grams: ic (raw) + lo cross (P=softmax) =======
// grid (32 k-chunks of 512, 16 jobs); each wave: one 128-k slab.
#define GR_PAD 136
__global__ __launch_bounds__(256) void gram_mfma_kernel(
    const float* __restrict__ s_out, const float* __restrict__ t_out,
    const float* __restrict__ zrbuf, float* __restrict__ Gs,
    float* __restrict__ Gt, float* __restrict__ cross) {
  __shared__ unsigned short st[4][32][GR_PAD];   // 34816 B; aliased as red later
  int job = blockIdx.y;
  int kind = job >> 3, tens = (job >> 2) & 1, b = job & 3;
  const float* x = (tens ? t_out : s_out) + b * 344064;
  const float* zr = zrbuf + ((tens * 4 + b) * 21) * 128;
  int tid = threadIdx.x, wave = tid >> 6, lane = tid & 63;
  int lrow = lane & 15, kblk = lane >> 4;
#pragma unroll
  for (int r = 21; r < 32; r++)
    *(unsigned int*)&st[wave][r][lane * 2] = 0u;
  f32x4 a00 = {0.f, 0.f, 0.f, 0.f}, a01 = {0.f, 0.f, 0.f, 0.f};
  f32x4 a11 = {0.f, 0.f, 0.f, 0.f};
  int k0 = blockIdx.x * 512 + wave * 128;
  for (int c = 0; c < 21; c++) {
    float2 v = *(const float2*)(x + c * 16384 + k0 + lane * 2);
    if (kind) {
      float2 z2 = *(const float2*)(zr + c * 128 + ((lane * 2) & 127));
      v.x = __expf(v.x) * z2.x;
      v.y = __expf(v.y) * z2.y;
    }
    unsigned int pk = (unsigned int)f2bf(v.x) | ((unsigned int)f2bf(v.y) << 16);
    *(unsigned int*)&st[wave][c][lane * 2] = pk;
  }
#pragma unroll
  for (int kk = 0; kk < 4; kk++) {
    short8 A0 = *(const short8*)&st[wave][lrow][kk * 32 + kblk * 8];
    short8 A1 = *(const short8*)&st[wave][16 + lrow][kk * 32 + kblk * 8];
    a00 = __builtin_amdgcn_mfma_f32_16x16x32_bf16(A0, A0, a00, 0, 0, 0);
    a01 = __builtin_amdgcn_mfma_f32_16x16x32_bf16(A0, A1, a01, 0, 0, 0);
    a11 = __builtin_amdgcn_mfma_f32_16x16x32_bf16(A1, A1, a11, 0, 0, 0);
  }
  __syncthreads();
  float* red = (float*)&st[0][0][0];   // [4][3][16][16]
#pragma unroll
  for (int i = 0; i < 4; i++) {
    int m = kblk * 4 + i;
    red[((wave * 3 + 0) * 16 + m) * 16 + lrow] = a00[i];
    red[((wave * 3 + 1) * 16 + m) * 16 + lrow] = a01[i];
    red[((wave * 3 + 2) * 16 + m) * 16 + lrow] = a11[i];
  }
  __syncthreads();
  if (tid < 441) {
    int i = tid / 21, j = tid - i * 21;
    float s = 0.f;
#pragma unroll
    for (int w = 0; w < 4; w++) {
      float v;
      if (i < 16)
        v = (j < 16) ? red[((w * 3 + 0) * 16 + i) * 16 + j]
                     : red[((w * 3 + 1) * 16 + i) * 16 + (j - 16)];
      else
        v = (j < 16) ? red[((w * 3 + 1) * 16 + j) * 16 + (i - 16)]
                     : red[((w * 3 + 2) * 16 + (i - 16)) * 16 + (j - 16)];
      s += v;
    }
    float* dst = kind ? (cross + tens * 441) : ((tens ? Gt : Gs) + b * 441);
    atomicAdd(&dst[i * 21 + j], s);
  }
}

// ============================ lo stats (zr + self-ent) ======================
// 256 threads: w = tid&127, half = tid>>7 covers h in [half*64, half*64+64).
__global__ __launch_bounds__(256) void lo_stats_kernel(
    const float* __restrict__ s_out, const float* __restrict__ t_out,
    float* __restrict__ zrbuf, float* __restrict__ self_ent) {
  int c = blockIdx.x, b = blockIdx.y, tens = blockIdx.z;
  const float* x = (tens ? t_out : s_out) + b * 344064 + c * 16384;
  int tid = threadIdx.x;
  int w = tid & 127, half = tid >> 7;
  float Z = 0.f, U = 0.f;
  int h0 = half * 64;
#pragma unroll 4
  for (int h = h0; h < h0 + 64; h++) {
    float v = x[h * 128 + w];
    float e = __expf(v);
    Z += e; U += v * e;
  }
  __shared__ float zs[128], us[128], r2[2];
  if (half) { zs[w] = Z; us[w] = U; }
  __syncthreads();
  if (!half) {
    Z += zs[w]; U += us[w];
    int idx = ((tens * 4 + b) * 21 + c) * 128 + w;
    zrbuf[idx] = 1.0f / Z;
    float se = U / Z - __logf(Z);
#pragma unroll
    for (int k = 1; k < 64; k <<= 1) se += __shfl_xor(se, k);
    if ((tid & 63) == 0) r2[tid >> 6] = se;
  }
  __syncthreads();
  if (tid == 0) atomicAdd(&self_ent[tens * 21 + c], r2[0] + r2[1]);
}

// ======== fused final: ic norm-diff + lo norm-diff + output scalars =========
__global__ __launch_bounds__(512) void final_kernel(
    const float* __restrict__ Gs, const float* __restrict__ Gt,
    const float* __restrict__ self_ent, const float* __restrict__ cross,
    const float* __restrict__ acc, float* __restrict__ out) {
  __shared__ float gs[441], gt[441], ns[21], nt_[21], rd[8];
  __shared__ float icv, lov;
  int tid = threadIdx.x;
  // ---- ic ----
  float total = 0.f;
  for (int b = 0; b < 4; b++) {
    __syncthreads();
    if (tid < 441) { gs[tid] = Gs[b * 441 + tid]; gt[tid] = Gt[b * 441 + tid]; }
    __syncthreads();
    if (tid < 21) {
      float a = 0.f, c2 = 0.f;
      for (int j = 0; j < 21; j++) {
        a += gs[tid * 21 + j] * gs[tid * 21 + j];
        c2 += gt[tid * 21 + j] * gt[tid * 21 + j];
      }
      ns[tid] = fmaxf(sqrtf(a), 1e-12f);
      nt_[tid] = fmaxf(sqrtf(c2), 1e-12f);
    }
    __syncthreads();
    if (tid < 441) {
      int i = tid / 21;
      float d = gs[tid] / ns[i] - gt[tid] / nt_[i];
      total += d * d;
    }
  }
#pragma unroll
  for (int k = 1; k < 64; k <<= 1) total += __shfl_xor(total, k);
  if ((tid & 63) == 0) rd[tid >> 6] = total;
  __syncthreads();
  if (tid == 0) {
    float s = 0.f;
    for (int i = 0; i < 8; i++) s += rd[i];
    icv = s;
  }
  __syncthreads();
  // ---- lo (reuse gs/gt as Ks/Kt) ----
  if (tid < 441) {
    int i = tid / 21, j = tid - i * 21;
    int mx_ = i > j ? i : j;
    gs[tid] = (self_ent[mx_] - cross[tid]) * 0.25f;
    gt[tid] = (self_ent[21 + mx_] - cross[441 + tid]) * 0.25f;
  }
  __syncthreads();
  if (tid < 21) {
    float a = 0.f, b2 = 0.f;
    for (int j = 0; j < 21; j++) {
      a += gs[tid * 21 + j] * gs[tid * 21 + j];
      b2 += gt[tid * 21 + j] * gt[tid * 21 + j];
    }
    ns[tid] = fmaxf(sqrtf(a), 1e-12f);
    nt_[tid] = fmaxf(sqrtf(b2), 1e-12f);
  }
  __syncthreads();
  float tot = 0.f;
  if (tid < 441) {
    int i = tid / 21;
    float d = gs[tid] / ns[i] - gt[tid] / nt_[i];
    tot = d * d;
  }
#pragma unroll
  for (int k = 1; k < 64; k <<= 1) tot += __shfl_xor(tot, k);
  if ((tid & 63) == 0) rd[tid >> 6] = tot;
  __syncthreads();
  if (tid == 0) {
    float s = 0.f;
    for (int i = 0; i < 8; i++) s += rd[i];
    lov = s;
    out[0] = acc[4] * (1.0f / 64.0f);                 // pa_loss
    out[1] = acc[0] * (1.0f / 1376256.0f);            // pi_loss
    out[2] = icv * (1.0f / 84.0f);                    // ic_loss
    out[3] = lov * (1.0f / 1764.0f);                  // lo_loss
    out[4] = sqrtf(acc[1]) * (1.0f / 21233664.0f);    // SA_loss (4*2304^2)
  }
}

// ============================================================================
extern "C" void kernel_launch(void* const* d_in, const int* in_sizes, int n_in,
                              void* d_out, int out_size, void* d_ws, size_t ws_size,
                              hipStream_t stream) {
  const float* t3 = (const float*)d_in[0];
  const float* s3 = (const float*)d_in[1];
  const float* t4 = (const float*)d_in[2];
  const float* s4 = (const float*)d_in[3];
  const float* t_out = (const float*)d_in[4];
  const float* s_out = (const float*)d_in[5];
  const float* WB = (const float*)d_in[6];
  const float* bB = (const float*)d_in[7];
  const float* WC = (const float*)d_in[8];
  const float* bC = (const float*)d_in[9];
  float* out = (float*)d_out;
  float* ws = (float*)d_ws;

  float* acc = ws;                           // 8
  float* self_ent = ws + 8;                  // 42  -> 50
  float* cross = ws + 50;                    // 882 -> 932
  float* Gs = ws + 932;                      // 1764 -> 2696
  float* Gt = ws + 2696;                     // 1764 -> 4460 (zeroed region end)
  float* pooled_s = ws + 4460;               // 2048 -> 6508
  float* pooled_t = ws + 6508;               // 2048 -> 8556
  float* zrbuf = ws + 8556;                  // 21504 -> 30060
  float* rowstats2 = ws + 30060;             // 8*9216*6 = 442368 -> 472428 (all written)
  unsigned short* T16u = (unsigned short*)(ws + 472428);    // 589824 bf16
  unsigned short* Ab16u = (unsigned short*)(ws + 767340);   // 589824 bf16
  unsigned short* Ac16u = (unsigned short*)(ws + 1062252);  // 589824 bf16
  unsigned short* Ts16u = (unsigned short*)(ws + 1357164);  // 589824 bf16
  unsigned short* Wp16u = (unsigned short*)(ws + 1652076);  // 73728 bf16

  hipMemsetAsync(ws, 0, 4460 * sizeof(float), stream);
  hipMemcpyAsync(d_out, (const void*)s_out, 1376256 * sizeof(float),
                 hipMemcpyDeviceToDevice, stream);

  prep_kernel<<<720, 256, 0, stream>>>(t3, s3, WB, WC, T16u, Ts16u, Wp16u);
  conv_mfma_kernel<<<dim3(144, 4), 256, 0, stream>>>(Ts16u, Wp16u, bB, bC, Ab16u, Ac16u);
  sa_partial_kernel<<<dim3(36, 4, 8), 256, 0, stream>>>(T16u, Ab16u, Ac16u, rowstats2);
  sa_final_kernel<<<36, 256, 0, stream>>>(rowstats2, acc);
  pool_kernel<<<512, 256, 0, stream>>>(t4, s4, pooled_t, pooled_s);
  pa_final_kernel<<<1, 256, 0, stream>>>(pooled_t, pooled_s, acc);
  pi_kernel<<<256, 256, 0, stream>>>(t_out, s_out, acc);
  lo_stats_kernel<<<dim3(21, 4, 2), 256, 0, stream>>>(s_out, t_out, zrbuf, self_ent);
  gram_mfma_kernel<<<dim3(32, 16), 256, 0, stream>>>(s_out, t_out, zrbuf, Gs, Gt, cross);
  final_kernel<<<1, 512, 0, stream>>>(Gs, Gt, self_ent, cross, acc, out + 1376256);
}

// Round 11
// 71.353 us; speedup vs baseline: 2.2743x; 1.4186x over previous
//
#include <hip/hip_runtime.h>
#include <math.h>

// ---------------------------------------------------------------------------
// Shapes:
// t_feat3/s_feat3: [4][64][48][48]  (147456 per batch) -> viewed flat [2304][64]
// t_feat4/s_feat4: [4][128][24][24]
// t_out/s_out:     [4][21][128][128] (344064 per batch, 16384 per class)
// W_B/W_C: [64][64][3][3], b_B/b_C: [64]
// Output: s_out copy (1376256 floats) then pa, pi, ic, lo, SA scalars.
// 5 dispatches: A(prep|pool|pi|lo_stats|copy|zero) -> B(conv|gram|pa_final)
//               -> C(sa_partial) -> D(sa_final) -> E(final)
// ---------------------------------------------------------------------------

typedef __attribute__((ext_vector_type(8))) short short8;   // 8 bf16 (4 VGPR)
typedef __attribute__((ext_vector_type(4))) float f32x4;
typedef __attribute__((ext_vector_type(8))) unsigned short u16x8;
typedef __attribute__((ext_vector_type(4))) unsigned short u16x4;

#define INV_SQRT48 0.14433756729740643f
#define GR_PAD 136

static __device__ __forceinline__ unsigned short f2bf(float x) {
  unsigned int u = __float_as_uint(x);
  unsigned int r = (u + 0x7fffu + ((u >> 16) & 1u)) >> 16;
  return (unsigned short)r;
}

// ========== Kernel A: prep | pool | pi | lo_stats | copy | zero =============
__global__ __launch_bounds__(256) void megaA_kernel(
    const float* __restrict__ t3, const float* __restrict__ s3,
    const float* __restrict__ WB, const float* __restrict__ WC,
    const float* __restrict__ t4, const float* __restrict__ s4,
    const float* __restrict__ t_out, const float* __restrict__ s_out,
    unsigned short* __restrict__ T16, unsigned short* __restrict__ Ts,
    unsigned short* __restrict__ Wp, float* __restrict__ pooled_t,
    float* __restrict__ pooled_s, float* __restrict__ pi_part,
    float* __restrict__ zrbuf, float* __restrict__ se_part,
    float* __restrict__ copy_dst, float* __restrict__ wz) {
  __shared__ float ld[64][65];
  __shared__ float zs[128], us[128], r2s[2], redp[4];
  int bx = blockIdx.x;
  int tid = threadIdx.x;
  if (bx < 288) {
    // t3 -> bf16 pre-scaled by 1/sqrt(48)
    int i = (bx * 256 + tid) * 8;
    float4 a = *(const float4*)(t3 + i);
    float4 b = *(const float4*)(t3 + i + 4);
    u16x8 v;
    v[0] = f2bf(a.x * INV_SQRT48); v[1] = f2bf(a.y * INV_SQRT48);
    v[2] = f2bf(a.z * INV_SQRT48); v[3] = f2bf(a.w * INV_SQRT48);
    v[4] = f2bf(b.x * INV_SQRT48); v[5] = f2bf(b.y * INV_SQRT48);
    v[6] = f2bf(b.z * INV_SQRT48); v[7] = f2bf(b.w * INV_SQRT48);
    *(u16x8*)(T16 + i) = v;
  } else if (bx < 432) {
    // s3 -> transposed bf16 [b][pix][ic]
    int t = bx - 288;
    int b = t / 36;
    int p0 = (t - b * 36) * 64;
    const float* src = s3 + b * 147456;
#pragma unroll
    for (int q = tid; q < 1024; q += 256) {
      int ic = q >> 4; int px = (q & 15) << 2;
      float4 v = *(const float4*)(src + ic * 2304 + p0 + px);
      ld[ic][px] = v.x; ld[ic][px + 1] = v.y; ld[ic][px + 2] = v.z; ld[ic][px + 3] = v.w;
    }
    __syncthreads();
    int pix = tid >> 2, icg = (tid & 3) * 16;
    u16x8 o0, o1;
#pragma unroll
    for (int j = 0; j < 8; j++) o0[j] = f2bf(ld[icg + j][pix]);
#pragma unroll
    for (int j = 0; j < 8; j++) o1[j] = f2bf(ld[icg + 8 + j][pix]);
    unsigned short* dst = Ts + b * 147456 + (p0 + pix) * 64 + icg;
    *(u16x8*)dst = o0;
    *(u16x8*)(dst + 8) = o1;
  } else if (bx < 720) {
    // weight pack [oc][ic][3][3] -> [conv][tap][oc][ic]
    int idx = (bx - 432) * 256 + tid;
    int conv = idx / 36864;
    int r = idx - conv * 36864;
    int tap = r >> 12;
    int r2 = r & 4095;
    int oc = r2 >> 6, ic = r2 & 63;
    const float* W = conv ? WC : WB;
    Wp[idx] = f2bf(W[oc * 576 + ic * 9 + tap]);
  } else if (bx < 1232) {
    // pa maxpool 12x12
    int widx = (bx - 720) * 4 + (tid >> 6);  // 0..2047
    int lane = tid & 63;
    int p = widx & 3, bc = widx >> 2;
    int py = p >> 1, px = p & 1;
    int base = bc * 576 + py * 288 + px * 12;
    float mt = -1e30f, ms = -1e30f;
    for (int e = lane; e < 144; e += 64) {
      int iy = e / 12, ix = e - iy * 12;
      int off = base + iy * 24 + ix;
      mt = fmaxf(mt, t4[off]);
      ms = fmaxf(ms, s4[off]);
    }
#pragma unroll
    for (int d = 1; d < 64; d <<= 1) {
      mt = fmaxf(mt, __shfl_xor(mt, d));
      ms = fmaxf(ms, __shfl_xor(ms, d));
    }
    if (lane == 0) { pooled_t[widx] = mt; pooled_s[widx] = ms; }
  } else if (bx < 1488) {
    // pi (elementwise-mean KL over class softmax), per-block partial
    int pbx = bx - 1232;
    int idx = pbx * 256 + tid;  // 0..65535
    int b = idx >> 14, rem = idx & 16383;
    const float* tp = t_out + b * 344064 + rem;
    const float* sp = s_out + b * 344064 + rem;
    float t[21], s[21];
#pragma unroll
    for (int c = 0; c < 21; c++) { t[c] = tp[c * 16384]; s[c] = sp[c * 16384]; }
    float mt = t[0], ms = s[0];
#pragma unroll
    for (int c = 1; c < 21; c++) { mt = fmaxf(mt, t[c]); ms = fmaxf(ms, s[c]); }
    float Zt = 0.f, Zs = 0.f;
#pragma unroll
    for (int c = 0; c < 21; c++) { Zt += __expf(t[c] - mt); Zs += __expf(s[c] - ms); }
    float lt = __logf(Zt), ls = __logf(Zs);
    float sum = 0.f;
#pragma unroll
    for (int c = 0; c < 21; c++) {
      float lq = t[c] - mt - lt;
      float lp = s[c] - ms - ls;
      sum += __expf(lq) * (lq - lp);
    }
#pragma unroll
    for (int k = 1; k < 64; k <<= 1) sum += __shfl_xor(sum, k);
    if ((tid & 63) == 0) redp[tid >> 6] = sum;
    __syncthreads();
    if (tid == 0) pi_part[pbx] = redp[0] + redp[1] + redp[2] + redp[3];
  } else if (bx < 1656) {
    // lo stats: zr + self-ent partial (per (c,b,tens) plain store)
    int r = bx - 1488;
    int c = r % 21;
    int rem = r / 21;
    int b = rem & 3, tens = rem >> 2;
    const float* x = (tens ? t_out : s_out) + b * 344064 + c * 16384;
    int w = tid & 127, half = tid >> 7;
    float Z = 0.f, U = 0.f;
    int h0 = half * 64;
#pragma unroll 4
    for (int h = h0; h < h0 + 64; h++) {
      float v = x[h * 128 + w];
      float e = __expf(v);
      Z += e; U += v * e;
    }
    if (half) { zs[w] = Z; us[w] = U; }
    __syncthreads();
    if (!half) {
      Z += zs[w]; U += us[w];
      int idx = ((tens * 4 + b) * 21 + c) * 128 + w;
      zrbuf[idx] = 1.0f / Z;
      float se = U / Z - __logf(Z);
#pragma unroll
      for (int k = 1; k < 64; k <<= 1) se += __shfl_xor(se, k);
      if ((tid & 63) == 0) r2s[tid >> 6] = se;
    }
    __syncthreads();
    if (tid == 0) se_part[(tens * 4 + b) * 21 + c] = r2s[0] + r2s[1];
  } else if (bx < 2328) {
    // s_out -> d_out copy
    int i = (bx - 1656) * 2048 + tid * 8;
    float4 v0 = *(const float4*)(s_out + i);
    float4 v1 = *(const float4*)(s_out + i + 4);
    *(float4*)(copy_dst + i) = v0;
    *(float4*)(copy_dst + i + 4) = v1;
  } else {
    // zero ws[0..4460) (acc + cross + Gs + Gt): atomic targets used in B
    int base = (bx - 2328) * 2048 + tid * 8;
#pragma unroll
    for (int j = 0; j < 8; j++) {
      int ii = base + j;
      if (ii < 4460) wz[ii] = 0.f;
    }
  }
}

// ============ Kernel B: conv (576) | gram (512) | pa_final (1) ==============
__global__ __launch_bounds__(256) void heavyB_kernel(
    const unsigned short* __restrict__ Ts, const unsigned short* __restrict__ Wp,
    const float* __restrict__ bB, const float* __restrict__ bC,
    unsigned short* __restrict__ Ab, unsigned short* __restrict__ Ac,
    const float* __restrict__ s_out, const float* __restrict__ t_out,
    const float* __restrict__ zrbuf, float* __restrict__ Gs,
    float* __restrict__ Gt, float* __restrict__ cross,
    const float* __restrict__ pooled_t, const float* __restrict__ pooled_s,
    float* __restrict__ acc) {
  __shared__ __align__(16) char smem[35072];
  int bx = blockIdx.x, tid = threadIdx.x;
  int wave = tid >> 6, lane = tid & 63;
  int lrow = lane & 15, kblk = lane >> 4;
  if (bx < 576) {
    // ---------- conv3x3 as 9-tap implicit GEMM, output *1/sqrt(48) ----------
    int b = bx / 144;
    int ptile = bx - b * 144;
    int conv = wave & 1;
    int ochalf = wave >> 1;
    int p = ptile * 16 + lrow;
    int y = p / 48, x = p - y * 48;
    const unsigned short* Tb = Ts + b * 147456;
    const unsigned short* Wc = Wp + conv * 36864;
    const short8 zz = {0, 0, 0, 0, 0, 0, 0, 0};
    f32x4 acc0 = {0.f, 0.f, 0.f, 0.f}, acc1 = {0.f, 0.f, 0.f, 0.f};
#pragma unroll
    for (int t = 0; t < 9; t++) {
      const int dy = t / 3 - 1, dx = t % 3 - 1;
      int yy = y + dy, xx = x + dx;
      bool valid = ((unsigned)yy < 48u) && ((unsigned)xx < 48u);
      int spix = valid ? (p + dy * 48 + dx) : p;
      const unsigned short* ap = Tb + spix * 64 + kblk * 8;
      short8 a0 = *(const short8*)ap;
      short8 a1 = *(const short8*)(ap + 32);
      if (!valid) { a0 = zz; a1 = zz; }
      const unsigned short* wp0 = Wc + (t * 64 + ochalf * 32 + lrow) * 64 + kblk * 8;
      short8 b00 = *(const short8*)wp0;
      short8 b01 = *(const short8*)(wp0 + 32);
      short8 b10 = *(const short8*)(wp0 + 1024);
      short8 b11 = *(const short8*)(wp0 + 1024 + 32);
      acc0 = __builtin_amdgcn_mfma_f32_16x16x32_bf16(a0, b00, acc0, 0, 0, 0);
      acc0 = __builtin_amdgcn_mfma_f32_16x16x32_bf16(a1, b01, acc0, 0, 0, 0);
      acc1 = __builtin_amdgcn_mfma_f32_16x16x32_bf16(a0, b10, acc1, 0, 0, 0);
      acc1 = __builtin_amdgcn_mfma_f32_16x16x32_bf16(a1, b11, acc1, 0, 0, 0);
    }
    const float* bias = conv ? bC : bB;
    unsigned short* dst = conv ? Ac : Ab;
    int oc0 = ochalf * 32 + lrow;
    int oc1 = oc0 + 16;
    float bi0 = bias[oc0], bi1 = bias[oc1];
    int pixb = ptile * 16 + kblk * 4;
    u16x4 o0, o1;
#pragma unroll
    for (int i = 0; i < 4; i++) {
      o0[i] = f2bf((acc0[i] + bi0) * INV_SQRT48);
      o1[i] = f2bf((acc1[i] + bi1) * INV_SQRT48);
    }
    *(u16x4*)(dst + b * 147456 + oc0 * 2304 + pixb) = o0;
    *(u16x4*)(dst + b * 147456 + oc1 * 2304 + pixb) = o1;
  } else if (bx < 1088) {
    // ---------- unified MFMA 21x21 grams: ic (raw) + lo cross (P) -----------
    int g = bx - 576;
    int job = g >> 5, kx = g & 31;
    int kind = job >> 3, tens = (job >> 2) & 1, b = job & 3;
    const float* x = (tens ? t_out : s_out) + b * 344064;
    const float* zr = zrbuf + ((tens * 4 + b) * 21) * 128;
    unsigned short (*st)[32][GR_PAD] =
        reinterpret_cast<unsigned short(*)[32][GR_PAD]>(smem);
#pragma unroll
    for (int r = 21; r < 32; r++)
      *(unsigned int*)&st[wave][r][lane * 2] = 0u;
    f32x4 a00 = {0.f, 0.f, 0.f, 0.f}, a01 = {0.f, 0.f, 0.f, 0.f};
    f32x4 a11 = {0.f, 0.f, 0.f, 0.f};
    int k0 = kx * 512 + wave * 128;
    for (int c = 0; c < 21; c++) {
      float2 v = *(const float2*)(x + c * 16384 + k0 + lane * 2);
      if (kind) {
        float2 z2 = *(const float2*)(zr + c * 128 + ((lane * 2) & 127));
        v.x = __expf(v.x) * z2.x;
        v.y = __expf(v.y) * z2.y;
      }
      unsigned int pk = (unsigned int)f2bf(v.x) | ((unsigned int)f2bf(v.y) << 16);
      *(unsigned int*)&st[wave][c][lane * 2] = pk;
    }
#pragma unroll
    for (int kk = 0; kk < 4; kk++) {
      short8 A0 = *(const short8*)&st[wave][lrow][kk * 32 + kblk * 8];
      short8 A1 = *(const short8*)&st[wave][16 + lrow][kk * 32 + kblk * 8];
      a00 = __builtin_amdgcn_mfma_f32_16x16x32_bf16(A0, A0, a00, 0, 0, 0);
      a01 = __builtin_amdgcn_mfma_f32_16x16x32_bf16(A0, A1, a01, 0, 0, 0);
      a11 = __builtin_amdgcn_mfma_f32_16x16x32_bf16(A1, A1, a11, 0, 0, 0);
    }
    __syncthreads();
    float* red = (float*)smem;   // [4][3][16][16]
#pragma unroll
    for (int i = 0; i < 4; i++) {
      int m = kblk * 4 + i;
      red[((wave * 3 + 0) * 16 + m) * 16 + lrow] = a00[i];
      red[((wave * 3 + 1) * 16 + m) * 16 + lrow] = a01[i];
      red[((wave * 3 + 2) * 16 + m) * 16 + lrow] = a11[i];
    }
    __syncthreads();
    if (tid < 441) {
      int i = tid / 21, j = tid - i * 21;
      float s = 0.f;
#pragma unroll
      for (int w = 0; w < 4; w++) {
        float v;
        if (i < 16)
          v = (j < 16) ? red[((w * 3 + 0) * 16 + i) * 16 + j]
                       : red[((w * 3 + 1) * 16 + i) * 16 + (j - 16)];
        else
          v = (j < 16) ? red[((w * 3 + 1) * 16 + j) * 16 + (i - 16)]
                       : red[((w * 3 + 2) * 16 + (i - 16)) * 16 + (j - 16)];
        s += v;
      }
      float* dst = kind ? (cross + tens * 441) : ((tens ? Gt : Gs) + b * 441);
      atomicAdd(&dst[i * 21 + j], s);
    }
  } else {
    // ----------------------------- pa_final ---------------------------------
    float* ps = (float*)smem;          // 2048
    float* pt = ps + 2048;             // 2048
    float* nrm = pt + 2048;            // 32
    float* sim = nrm + 32;             // 128
    for (int q = tid; q < 2048; q += 256) { ps[q] = pooled_s[q]; pt[q] = pooled_t[q]; }
    __syncthreads();
    if (tid < 32) {
      int tens = tid >> 4, r = tid & 15, b = r >> 2, p = r & 3;
      const float* v = tens ? pt : ps;
      float s = 0.f;
      for (int c = 0; c < 128; c++) { float x = v[(b * 128 + c) * 4 + p]; s += x * x; }
      nrm[tid] = sqrtf(s) + 1e-8f;
    }
    __syncthreads();
    if (tid < 128) {
      int tens = tid >> 6, r = tid & 63, b = r >> 4, m = (r >> 2) & 3, n = r & 3;
      const float* v = tens ? pt : ps;
      float s = 0.f;
      for (int c = 0; c < 128; c++)
        s += v[(b * 128 + c) * 4 + m] * v[(b * 128 + c) * 4 + n];
      sim[tid] = s / (nrm[tens * 16 + b * 4 + m] * nrm[tens * 16 + b * 4 + n]);
    }
    __syncthreads();
    if (tid < 64) {
      float df = sim[64 + tid] - sim[tid];
      float d = df * df;
#pragma unroll
      for (int k = 1; k < 64; k <<= 1) d += __shfl_xor(d, k);
      if (tid == 0) acc[4] = d;   // raw; finalized /64 in E
    }
  }
}

// ========= Kernel C: SA counted-vmcnt 3-buffer pipeline (R10 body) ==========
__global__ __launch_bounds__(256) void sa_partial_kernel(
    const unsigned short* __restrict__ T16, const unsigned short* __restrict__ Ab16,
    const unsigned short* __restrict__ Ac16, float* __restrict__ rowstats2) {
  __shared__ __align__(16) unsigned short lbuf[3][2][2048];  // 24 KB, 3 buffers
  int b = blockIdx.y, zc = blockIdx.z;
  int r0 = blockIdx.x * 64;
  const unsigned short* Tb = T16 + b * 147456;
  const unsigned short* Abb = Ab16 + b * 147456;
  const unsigned short* Acb = Ac16 + b * 147456;
  int tid = threadIdx.x, wave = tid >> 6, lane = tid & 63;
  int lrow = lane & 15, kblk = lane >> 4;
  int grow_base = r0 + wave * 16;
  const short8 at0 = *(const short8*)(Tb + (grow_base + lrow) * 64 + kblk * 8);
  const short8 at1 = *(const short8*)(Tb + (grow_base + lrow) * 64 + 32 + kblk * 8);
  const short8 ar0 = *(const short8*)(Abb + (grow_base + lrow) * 64 + kblk * 8);
  const short8 ar1 = *(const short8*)(Abb + (grow_base + lrow) * 64 + 32 + kblk * 8);
  const unsigned short* sarr = (wave & 2) ? Acb : Tb;
  int aw = wave >> 1, hw = wave & 1;

  float Sx[4] = {0.f, 0.f, 0.f, 0.f}, Sa[4] = {0.f, 0.f, 0.f, 0.f};
  float Sa2[4] = {0.f, 0.f, 0.f, 0.f}, Zb[4] = {0.f, 0.f, 0.f, 0.f};
  float Qq[4] = {0.f, 0.f, 0.f, 0.f}, Ww[4] = {0.f, 0.f, 0.f, 0.f};

#define SA_STAGE(s_, p_)                                                        \
  {                                                                             \
    int n0_ = zc * 288 + (s_) * 32;                                             \
    const char* gb_ = (const char*)(sarr + n0_ * 64);                           \
    char* lb_ = (char*)(&lbuf[(p_)][aw][0]);                                    \
    _Pragma("unroll")                                                           \
    for (int j_ = 0; j_ < 2; j_++) {                                            \
      int d_ = hw * 2048 + j_ * 1024 + lane * 16;                               \
      int g_ = d_ ^ (((d_ >> 7) & 7) << 4);                                     \
      __builtin_amdgcn_global_load_lds(                                         \
          (const __attribute__((address_space(1))) unsigned int*)(gb_ + g_),    \
          (__attribute__((address_space(3))) unsigned int*)(lb_ + hw * 2048 + j_ * 1024), \
          16, 0, 0);                                                            \
    }                                                                           \
  }

  SA_STAGE(0, 0);
  SA_STAGE(1, 1);
#pragma unroll 1
  for (int s = 0; s < 9; s++) {
    if (s < 8) asm volatile("s_waitcnt vmcnt(2)" ::: "memory");
    else       asm volatile("s_waitcnt vmcnt(0)" ::: "memory");
    __builtin_amdgcn_sched_barrier(0);
    __builtin_amdgcn_s_barrier();
    __builtin_amdgcn_sched_barrier(0);
    if (s + 2 <= 8) SA_STAGE(s + 2, (s + 2) % 3);
    int p = s % 3;
    int n0 = zc * 288 + s * 32;
    const char* lbT = (const char*)&lbuf[p][0][0];
    const char* lbC = (const char*)&lbuf[p][1][0];
    int sw = (lrow & 7) << 4;
#pragma unroll
    for (int ctl = 0; ctl < 2; ctl++) {
      int abase = (ctl * 16 + lrow) * 128 + kblk * 16;
      short8 bt0 = *(const short8*)(lbT + (abase ^ sw));
      short8 bt1 = *(const short8*)(lbT + ((abase + 64) ^ sw));
      short8 bc0 = *(const short8*)(lbC + (abase ^ sw));
      short8 bc1 = *(const short8*)(lbC + ((abase + 64) ^ sw));
      f32x4 accA = {0.f, 0.f, 0.f, 0.f}, accV = {0.f, 0.f, 0.f, 0.f};
      accA = __builtin_amdgcn_mfma_f32_16x16x32_bf16(at0, bt0, accA, 0, 0, 0);
      accA = __builtin_amdgcn_mfma_f32_16x16x32_bf16(at1, bt1, accA, 0, 0, 0);
      accV = __builtin_amdgcn_mfma_f32_16x16x32_bf16(ar0, bc0, accV, 0, 0, 0);
      accV = __builtin_amdgcn_mfma_f32_16x16x32_bf16(ar1, bc1, accV, 0, 0, 0);
      int col = n0 + ctl * 16 + lrow;
#pragma unroll
      for (int i = 0; i < 4; i++) {
        int row = grow_base + kblk * 4 + i;
        float a = accA[i];
        float v = accV[i];
        if (row == col) { a = 0.f; v = 0.f; }
        float ea = __expf(a), eb = __expf(v);
        Sx[i] += ea; Sa[i] += a; Sa2[i] += a * a;
        Zb[i] += eb; Qq[i] += eb * eb; Ww[i] += a * eb;
      }
    }
  }
#pragma unroll
  for (int m = 1; m < 16; m <<= 1) {
#pragma unroll
    for (int i = 0; i < 4; i++) {
      Sx[i] += __shfl_xor(Sx[i], m);
      Sa[i] += __shfl_xor(Sa[i], m);
      Sa2[i] += __shfl_xor(Sa2[i], m);
      Zb[i] += __shfl_xor(Zb[i], m);
      Qq[i] += __shfl_xor(Qq[i], m);
      Ww[i] += __shfl_xor(Ww[i], m);
    }
  }
  if (lrow == 0) {
#pragma unroll
    for (int i = 0; i < 4; i++) {
      int row = grow_base + kblk * 4 + i;
      float* rp = &rowstats2[((size_t)zc * 9216 + b * 2304 + row) * 6];
      rp[0] = Sx[i]; rp[1] = Sa[i]; rp[2] = Sa2[i];
      rp[3] = Zb[i]; rp[4] = Qq[i]; rp[5] = Ww[i];
    }
  }
#undef SA_STAGE
}

// ====== Kernel D: SA 8-way reduce + rowloss -> sa_part (plain store) ========
__global__ __launch_bounds__(256) void sa_final_kernel(
    const float* __restrict__ rowstats2, float* __restrict__ sa_part) {
  int row = blockIdx.x * 256 + threadIdx.x;   // 0..9215
  float st[6] = {0.f, 0.f, 0.f, 0.f, 0.f, 0.f};
#pragma unroll
  for (int z = 0; z < 8; z++) {
    const float* rp = rowstats2 + ((size_t)z * 9216 + row) * 6;
#pragma unroll
    for (int s = 0; s < 6; s++) st[s] += rp[s];
  }
  float L = __logf(st[0]);
  float rl = st[2] - 2.f * L * st[1] + 2304.f * L * L + 2.f * L
             - 2.f * (st[5] / st[3]) + st[4] / (st[3] * st[3]);
  __shared__ float red[4];
#pragma unroll
  for (int m = 1; m < 64; m <<= 1) rl += __shfl_xor(rl, m);
  if ((threadIdx.x & 63) == 0) red[threadIdx.x >> 6] = rl;
  __syncthreads();
  if (threadIdx.x == 0)
    sa_part[blockIdx.x] = red[0] + red[1] + red[2] + red[3];
}

// ========== Kernel E: final — ic + lo norm-diffs + all output scalars =======
__global__ __launch_bounds__(512) void final_kernel(
    const float* __restrict__ Gs, const float* __restrict__ Gt,
    const float* __restrict__ se_part, const float* __restrict__ cross,
    const float* __restrict__ pi_part, const float* __restrict__ sa_part,
    const float* __restrict__ acc, float* __restrict__ out) {
  __shared__ float gs[441], gt[441], ns[21], nt_[21], rd[8], rd2[8], se_sh[42];
  __shared__ float icv, pis, sas;
  int tid = threadIdx.x;
  // ---- phase 0: pi/sa partial sums + se sums ----
  float pv = (tid < 256) ? pi_part[tid] : 0.f;
  float sv = (tid < 36) ? sa_part[tid] : 0.f;
#pragma unroll
  for (int k = 1; k < 64; k <<= 1) {
    pv += __shfl_xor(pv, k);
    sv += __shfl_xor(sv, k);
  }
  if ((tid & 63) == 0) { rd[tid >> 6] = pv; rd2[tid >> 6] = sv; }
  if (tid < 42) {
    int tens = tid / 21, c = tid - tens * 21;
    float s = 0.f;
    for (int b = 0; b < 4; b++) s += se_part[(tens * 4 + b) * 21 + c];
    se_sh[tid] = s;
  }
  __syncthreads();
  if (tid == 0) {
    float p = 0.f, s = 0.f;
    for (int i = 0; i < 8; i++) { p += rd[i]; s += rd2[i]; }
    pis = p; sas = s;
  }
  __syncthreads();
  // ---- ic ----
  float total = 0.f;
  for (int b = 0; b < 4; b++) {
    __syncthreads();
    if (tid < 441) { gs[tid] = Gs[b * 441 + tid]; gt[tid] = Gt[b * 441 + tid]; }
    __syncthreads();
    if (tid < 21) {
      float a = 0.f, c2 = 0.f;
      for (int j = 0; j < 21; j++) {
        a += gs[tid * 21 + j] * gs[tid * 21 + j];
        c2 += gt[tid * 21 + j] * gt[tid * 21 + j];
      }
      ns[tid] = fmaxf(sqrtf(a), 1e-12f);
      nt_[tid] = fmaxf(sqrtf(c2), 1e-12f);
    }
    __syncthreads();
    if (tid < 441) {
      int i = tid / 21;
      float d = gs[tid] / ns[i] - gt[tid] / nt_[i];
      total += d * d;
    }
  }
#pragma unroll
  for (int k = 1; k < 64; k <<= 1) total += __shfl_xor(total, k);
  if ((tid & 63) == 0) rd[tid >> 6] = total;
  __syncthreads();
  if (tid == 0) {
    float s = 0.f;
    for (int i = 0; i < 8; i++) s += rd[i];
    icv = s;
  }
  __syncthreads();
  // ---- lo (reuse gs/gt as Ks/Kt) ----
  if (tid < 441) {
    int i = tid / 21, j = tid - i * 21;
    int mx_ = i > j ? i : j;
    gs[tid] = (se_sh[mx_] - cross[tid]) * 0.25f;
    gt[tid] = (se_sh[21 + mx_] - cross[441 + tid]) * 0.25f;
  }
  __syncthreads();
  if (tid < 21) {
    float a = 0.f, b2 = 0.f;
    for (int j = 0; j < 21; j++) {
      a += gs[tid * 21 + j] * gs[tid * 21 + j];
      b2 += gt[tid * 21 + j] * gt[tid * 21 + j];
    }
    ns[tid] = fmaxf(sqrtf(a), 1e-12f);
    nt_[tid] = fmaxf(sqrtf(b2), 1e-12f);
  }
  __syncthreads();
  float tot = 0.f;
  if (tid < 441) {
    int i = tid / 21;
    float d = gs[tid] / ns[i] - gt[tid] / nt_[i];
    tot = d * d;
  }
#pragma unroll
  for (int k = 1; k < 64; k <<= 1) tot += __shfl_xor(tot, k);
  if ((tid & 63) == 0) rd[tid >> 6] = tot;
  __syncthreads();
  if (tid == 0) {
    float lov = 0.f;
    for (int i = 0; i < 8; i++) lov += rd[i];
    out[0] = acc[4] * (1.0f / 64.0f);                 // pa_loss
    out[1] = pis * (1.0f / 1376256.0f);               // pi_loss
    out[2] = icv * (1.0f / 84.0f);                    // ic_loss
    out[3] = lov * (1.0f / 1764.0f);                  // lo_loss
    out[4] = sqrtf(sas) * (1.0f / 21233664.0f);       // SA_loss (4*2304^2)
  }
}

// ============================================================================
extern "C" void kernel_launch(void* const* d_in, const int* in_sizes, int n_in,
                              void* d_out, int out_size, void* d_ws, size_t ws_size,
                              hipStream_t stream) {
  const float* t3 = (const float*)d_in[0];
  const float* s3 = (const float*)d_in[1];
  const float* t4 = (const float*)d_in[2];
  const float* s4 = (const float*)d_in[3];
  const float* t_out = (const float*)d_in[4];
  const float* s_out = (const float*)d_in[5];
  const float* WB = (const float*)d_in[6];
  const float* bB = (const float*)d_in[7];
  const float* WC = (const float*)d_in[8];
  const float* bC = (const float*)d_in[9];
  float* out = (float*)d_out;
  float* ws = (float*)d_ws;

  float* acc = ws;                            // [0, 8)
  float* cross = ws + 8;                      // [8, 890)
  float* Gs = ws + 890;                       // [890, 2654)
  float* Gt = ws + 2654;                      // [2654, 4418)  zero region: [0,4460)
  float* se_part = ws + 4460;                 // 168
  float* pi_part = ws + 4628;                 // 256
  float* sa_part = ws + 4884;                 // 36
  float* pooled_s = ws + 4920;                // 2048
  float* pooled_t = ws + 6968;                // 2048
  float* zrbuf = ws + 9016;                   // 21504 -> 30520
  float* rowstats2 = ws + 30520;              // 442368 -> 472888 (all written)
  unsigned short* T16u = (unsigned short*)(ws + 472888);    // 589824 bf16
  unsigned short* Ab16u = (unsigned short*)(ws + 767800);   // 589824 bf16
  unsigned short* Ac16u = (unsigned short*)(ws + 1062712);  // 589824 bf16
  unsigned short* Ts16u = (unsigned short*)(ws + 1357624);  // 589824 bf16
  unsigned short* Wp16u = (unsigned short*)(ws + 1652536);  // 73728 bf16

  megaA_kernel<<<2331, 256, 0, stream>>>(
      t3, s3, WB, WC, t4, s4, t_out, s_out,
      T16u, Ts16u, Wp16u, pooled_t, pooled_s, pi_part, zrbuf, se_part,
      out, acc);
  heavyB_kernel<<<1089, 256, 0, stream>>>(
      Ts16u, Wp16u, bB, bC, Ab16u, Ac16u,
      s_out, t_out, zrbuf, Gs, Gt, cross, pooled_t, pooled_s, acc);
  sa_partial_kernel<<<dim3(36, 4, 8), 256, 0, stream>>>(T16u, Ab16u, Ac16u, rowstats2);
  sa_final_kernel<<<36, 256, 0, stream>>>(rowstats2, sa_part);
  final_kernel<<<1, 512, 0, stream>>>(Gs, Gt, se_part, cross, pi_part, sa_part,
                                      acc, out + 1376256);
}